// Round 3
// baseline (762.734 us; speedup 1.0000x reference)
//
#include <hip/hip_runtime.h>
#include <hip/hip_bf16.h>
#include <math.h>

#define T 2048
#define C 2048
#define NH 16
#define HD 128
#define SCALE 0.08838834764831845f   // 1/sqrt(128)

typedef short s16x8 __attribute__((ext_vector_type(8)));
typedef float f32x4 __attribute__((ext_vector_type(4)));
typedef float f32x2 __attribute__((ext_vector_type(2)));

__device__ __forceinline__ float wave_sum(float v) {
  #pragma unroll
  for (int o = 32; o > 0; o >>= 1) v += __shfl_xor(v, o, 64);
  return v;
}
// RNE fp32->bf16
__device__ __forceinline__ unsigned short f2bf(float f) {
  unsigned u = __float_as_uint(f);
  u += 0x7FFFu + ((u >> 16) & 1u);
  return (unsigned short)(u >> 16);
}
__device__ __forceinline__ float hv(f32x2 v, int h) { return h ? v.y : v.x; }

// ---------------- fp32 -> bf16 pre-convert (elementwise) ----------------
__global__ __launch_bounds__(256) void to_bf16(const float* __restrict__ in,
                                               unsigned short* __restrict__ outp,
                                               int n4) {
  int i = blockIdx.x * blockDim.x + threadIdx.x;
  const int stride = gridDim.x * blockDim.x;
  for (; i < n4; i += stride) {
    float4 v = ((const float4*)in)[i];
    ushort4 o;
    o.x = f2bf(v.x); o.y = f2bf(v.y); o.z = f2bf(v.z); o.w = f2bf(v.w);
    ((ushort4*)outp)[i] = o;
  }
}

// ---------------- FROZEN fp32 Q/K GEMM, double-buffered, pk-packed --------
// Per-element FP sequence identical to the validated round-5 kernel:
// k ascending, 4 partials by k&3, FMA chain, pairwise merge. v_pk_fma_f32
// computes two independent IEEE fp32 FMAs (lo/hi) — element (i,j) = (2ip+h, j)
// executes exactly acc += ar[i]*br[j] in the same order => BIT-IDENTICAL.
// Only instruction packing changed (rounding-free). Do NOT alter semantics.
#define TM 128
#define TN 64
#define GBK 16

__global__ __launch_bounds__(256) void gemm_qk(const float* __restrict__ A,
                                               const float* __restrict__ Wq,
                                               const float* __restrict__ Wk,
                                               float* __restrict__ Qo,
                                               float* __restrict__ Ko) {
  const float* __restrict__ Bw = blockIdx.z ? Wk : Wq;
  float* __restrict__ Cc = blockIdx.z ? Ko : Qo;
  __shared__ float As[2][GBK][TM + 4];
  __shared__ float Bs[2][GBK][TN + 4];
  const int tid = threadIdx.x;
  const int bm = blockIdx.x * TM;
  const int bn = blockIdx.y * TN;
  const int tm = (tid >> 4) * 8;
  const int tn = (tid & 15) * 4;
  const int sr = tid >> 2;            // staging row (chunk 0); chunk 1 = sr+64
  const int sc4 = (tid & 3) * 4;      // staging k offset

  // acc2[p][ip][j]: lo half = element i=2ip, hi half = i=2ip+1
  f32x2 acc2[4][4][4];
  #pragma unroll
  for (int p = 0; p < 4; ++p)
    #pragma unroll
    for (int ip = 0; ip < 4; ++ip)
      #pragma unroll
      for (int j = 0; j < 4; ++j) acc2[p][ip][j] = (f32x2){0.f, 0.f};

  // prologue: stage iter 0 into buffer 0
  {
    float4 a0 = *(const float4*)(A + (size_t)(bm + sr) * C + sc4);
    float4 a1 = *(const float4*)(A + (size_t)(bm + 64 + sr) * C + sc4);
    float4 b0 = *(const float4*)(Bw + (size_t)(bn + sr) * C + sc4);
    As[0][sc4 + 0][sr] = a0.x; As[0][sc4 + 1][sr] = a0.y;
    As[0][sc4 + 2][sr] = a0.z; As[0][sc4 + 3][sr] = a0.w;
    As[0][sc4 + 0][64 + sr] = a1.x; As[0][sc4 + 1][64 + sr] = a1.y;
    As[0][sc4 + 2][64 + sr] = a1.z; As[0][sc4 + 3][64 + sr] = a1.w;
    Bs[0][sc4 + 0][sr] = b0.x; Bs[0][sc4 + 1][sr] = b0.y;
    Bs[0][sc4 + 2][sr] = b0.z; Bs[0][sc4 + 3][sr] = b0.w;
  }
  __syncthreads();

  const int niter = C / GBK;
  for (int it = 0; it < niter; ++it) {
    const int cur = it & 1;
    const bool has = (it + 1) < niter;
    float4 a0n, a1n, b0n;
    if (has) {
      const int k0 = (it + 1) * GBK;
      a0n = *(const float4*)(A + (size_t)(bm + sr) * C + k0 + sc4);
      a1n = *(const float4*)(A + (size_t)(bm + 64 + sr) * C + k0 + sc4);
      b0n = *(const float4*)(Bw + (size_t)(bn + sr) * C + k0 + sc4);
    }
    #pragma unroll
    for (int k = 0; k < GBK; ++k) {
      float4 a0 = *(const float4*)&As[cur][k][tm];
      float4 a1 = *(const float4*)&As[cur][k][tm + 4];
      float4 bv = *(const float4*)&Bs[cur][k][tn];
      f32x2 ar2[4];
      ar2[0] = (f32x2){a0.x, a0.y}; ar2[1] = (f32x2){a0.z, a0.w};
      ar2[2] = (f32x2){a1.x, a1.y}; ar2[3] = (f32x2){a1.z, a1.w};
      f32x2 br2[4];
      br2[0] = (f32x2){bv.x, bv.x}; br2[1] = (f32x2){bv.y, bv.y};
      br2[2] = (f32x2){bv.z, bv.z}; br2[3] = (f32x2){bv.w, bv.w};
      const int p = k & 3;
      #pragma unroll
      for (int ip = 0; ip < 4; ++ip)
        #pragma unroll
        for (int j = 0; j < 4; ++j)
          asm("v_pk_fma_f32 %0, %1, %2, %0"
              : "+v"(acc2[p][ip][j])
              : "v"(ar2[ip]), "v"(br2[j]));
    }
    if (has) {
      const int nxt = cur ^ 1;
      As[nxt][sc4 + 0][sr] = a0n.x; As[nxt][sc4 + 1][sr] = a0n.y;
      As[nxt][sc4 + 2][sr] = a0n.z; As[nxt][sc4 + 3][sr] = a0n.w;
      As[nxt][sc4 + 0][64 + sr] = a1n.x; As[nxt][sc4 + 1][64 + sr] = a1n.y;
      As[nxt][sc4 + 2][64 + sr] = a1n.z; As[nxt][sc4 + 3][64 + sr] = a1n.w;
      Bs[nxt][sc4 + 0][sr] = b0n.x; Bs[nxt][sc4 + 1][sr] = b0n.y;
      Bs[nxt][sc4 + 2][sr] = b0n.z; Bs[nxt][sc4 + 3][sr] = b0n.w;
    }
    __syncthreads();
  }
  // merge: (p0+p1)+(p2+p3) per element — identical tree to frozen kernel
  #pragma unroll
  for (int ip = 0; ip < 4; ++ip)
    #pragma unroll
    for (int h = 0; h < 2; ++h) {
      float4 o;
      o.x = (hv(acc2[0][ip][0], h) + hv(acc2[1][ip][0], h)) +
            (hv(acc2[2][ip][0], h) + hv(acc2[3][ip][0], h));
      o.y = (hv(acc2[0][ip][1], h) + hv(acc2[1][ip][1], h)) +
            (hv(acc2[2][ip][1], h) + hv(acc2[3][ip][1], h));
      o.z = (hv(acc2[0][ip][2], h) + hv(acc2[1][ip][2], h)) +
            (hv(acc2[2][ip][2], h) + hv(acc2[3][ip][2], h));
      o.w = (hv(acc2[0][ip][3], h) + hv(acc2[1][ip][3], h)) +
            (hv(acc2[2][ip][3], h) + hv(acc2[3][ip][3], h));
      *(float4*)(Cc + (size_t)(bm + tm + 2 * ip + h) * C + bn + tn) = o;
    }
}

// ---------------- bf16 MFMA GEMM (smooth paths), pre-converted inputs ------
// C[m][n] = sum_k A[m,k]*B[n,k]; A,B bf16 k-major; fp32 out.
// Tile 64x128, BK=32, double-buffered, XOR-swizzled LDS (2-way = free).
#define VBM 64
#define VBN 128
#define VBK 32

__global__ __launch_bounds__(256) void gemm_bf16n(const unsigned short* __restrict__ A,
                                                  const unsigned short* __restrict__ B,
                                                  float* __restrict__ Cc) {
  __shared__ unsigned short Al[2][VBM * VBK];   // 2 x 4 KB
  __shared__ unsigned short Bl[2][VBN * VBK];   // 2 x 8 KB
  const int tid = threadIdx.x;
  const int bm = blockIdx.x * VBM;
  const int bn = blockIdx.y * VBN;
  const int wv = tid >> 6, lane = tid & 63;
  const int wm = wv & 1, wn = wv >> 1;
  const int lrow = lane & 15, lquad = lane >> 4;

  // staging: chunk = (row, qg); lds slot q = qg ^ ((row>>1)&3)
  const int a_row = tid >> 2, qg = tid & 3;
  const int a_qs = qg ^ ((a_row >> 1) & 3);
  const int b_row0 = tid >> 2;            // b chunk 1 row = b_row0+64, same swz
  const int b_qs = qg ^ ((b_row0 >> 1) & 3);

  f32x4 acc[2][4];
  #pragma unroll
  for (int i = 0; i < 2; ++i)
    #pragma unroll
    for (int j = 0; j < 4; ++j) acc[i][j] = (f32x4){0.f, 0.f, 0.f, 0.f};

  // prologue: stage iter 0 into buffer 0
  {
    uint4 av = *(const uint4*)(A + (size_t)(bm + a_row) * C + qg * 8);
    uint4 b0 = *(const uint4*)(B + (size_t)(bn + b_row0) * C + qg * 8);
    uint4 b1 = *(const uint4*)(B + (size_t)(bn + 64 + b_row0) * C + qg * 8);
    *(uint4*)&Al[0][a_row * VBK + a_qs * 8] = av;
    *(uint4*)&Bl[0][b_row0 * VBK + b_qs * 8] = b0;
    *(uint4*)&Bl[0][(64 + b_row0) * VBK + b_qs * 8] = b1;
  }
  __syncthreads();

  const int niter = C / VBK;
  for (int it = 0; it < niter; ++it) {
    const int cur = it & 1;
    const bool has = (it + 1) < niter;
    uint4 avn, b0n, b1n;
    if (has) {
      const int k0 = (it + 1) * VBK;
      avn = *(const uint4*)(A + (size_t)(bm + a_row) * C + k0 + qg * 8);
      b0n = *(const uint4*)(B + (size_t)(bn + b_row0) * C + k0 + qg * 8);
      b1n = *(const uint4*)(B + (size_t)(bn + 64 + b_row0) * C + k0 + qg * 8);
    }
    s16x8 af[2], bfr[4];
    #pragma unroll
    for (int mi = 0; mi < 2; ++mi) {
      const int r = wm * 32 + mi * 16 + lrow;
      const int q = lquad ^ ((r >> 1) & 3);
      af[mi] = *(const s16x8*)&Al[cur][r * VBK + q * 8];
    }
    #pragma unroll
    for (int ni = 0; ni < 4; ++ni) {
      const int r = wn * 64 + ni * 16 + lrow;
      const int q = lquad ^ ((r >> 1) & 3);
      bfr[ni] = *(const s16x8*)&Bl[cur][r * VBK + q * 8];
    }
    #pragma unroll
    for (int mi = 0; mi < 2; ++mi)
      #pragma unroll
      for (int ni = 0; ni < 4; ++ni)
        acc[mi][ni] = __builtin_amdgcn_mfma_f32_16x16x32_bf16(af[mi], bfr[ni], acc[mi][ni], 0, 0, 0);
    if (has) {
      const int nxt = cur ^ 1;
      *(uint4*)&Al[nxt][a_row * VBK + a_qs * 8] = avn;
      *(uint4*)&Bl[nxt][b_row0 * VBK + b_qs * 8] = b0n;
      *(uint4*)&Bl[nxt][(64 + b_row0) * VBK + b_qs * 8] = b1n;
    }
    __syncthreads();
  }
  // epilogue: C/D layout col=lane&15, row=lquad*4+r (m89-verified)
  #pragma unroll
  for (int mi = 0; mi < 2; ++mi)
    #pragma unroll
    for (int ni = 0; ni < 4; ++ni)
      #pragma unroll
      for (int r = 0; r < 4; ++r) {
        int row = bm + wm * 32 + mi * 16 + lquad * 4 + r;
        int col = bn + wn * 64 + ni * 16 + lrow;
        Cc[(size_t)row * C + col] = acc[mi][ni][r];
      }
}

// ---------------- RoPE + RMSNorm + bucket codes (FROZEN), fused z ----------
__global__ __launch_bounds__(256) void rope_fused(float* __restrict__ Qb,
                                                  float* __restrict__ Kb,
                                                  const float* __restrict__ cosb,
                                                  const float* __restrict__ sinb,
                                                  const float* __restrict__ Wdq,
                                                  const float* __restrict__ Wdk,
                                                  int* __restrict__ qcodes,
                                                  int* __restrict__ kcodes) {
  float* __restrict__ buf = blockIdx.y ? Kb : Qb;
  const float* __restrict__ Wd = blockIdx.y ? Wdk : Wdq;
  int* __restrict__ codes = blockIdx.y ? kcodes : qcodes;
  int wave = (blockIdx.x << 2) + (threadIdx.x >> 6);
  int lane = threadIdx.x & 63;
  int t = wave / NH, h = wave % NH;
  size_t base = (size_t)t * C + h * HD;
  float x1 = buf[base + lane];
  float x2 = buf[base + lane + 64];
  float c = cosb[t * 64 + lane];
  float s = sinb[t * 64 + lane];
  float r1 = x1 * c + x2 * s;
  float r2 = x2 * c - x1 * s;       // -x1*s + x2*c
  float ss = wave_sum(r1 * r1 + r2 * r2);
  float inv = 1.0f / sqrtf(ss * (1.0f / 128.0f) + 1e-6f);
  r1 *= inv; r2 *= inv;
  buf[base + lane] = r1;
  buf[base + lane + 64] = r2;
  int code = 0;
  #pragma unroll
  for (int kk = 0; kk < 7; ++kk) {
    float z = r1 * Wd[kk * HD + lane] + r2 * Wd[kk * HD + lane + 64];
    z = wave_sum(z);
    float sig = 1.0f / (1.0f + expf(-z));
    if (sig * 1.99f >= 1.0f) code |= (1 << kk);
  }
  if (lane == 0) codes[h * T + t] = code;
}

// ---------------- sparse ballot-scan attention (validated round 7) ---------
__global__ __launch_bounds__(256) void attn_sparse(const float* __restrict__ Q,
                                                   const float* __restrict__ Kn,
                                                   const float* __restrict__ V,
                                                   const int* __restrict__ qc,
                                                   const int* __restrict__ kc,
                                                   float* __restrict__ Y) {
  const int tid = threadIdx.x;
  const int lane = tid & 63;
  const int wave_id = blockIdx.x * 4 + (tid >> 6);   // [0, T*NH)
  const int h = wave_id & (NH - 1);
  const int qrow = wave_id >> 4;
  const size_t hb = (size_t)h * HD;

  const float q0 = Q[(size_t)qrow * C + hb + lane];
  const float q1 = Q[(size_t)qrow * C + hb + lane + 64];
  const int qcode = qc[h * T + qrow];
  const int* kch = kc + h * T;

  float m = -1e30f, l = 0.f, acc0 = 0.f, acc1 = 0.f;

  const int nchunks = (qrow >> 6) + 1;
  int kcj = kch[lane];
  for (int ci = 0; ci < nchunks; ++ci) {
    const int j0 = ci << 6;
    const int cur = kcj;
    if (ci + 1 < nchunks) kcj = kch[j0 + 64 + lane];
    unsigned long long mask = __ballot((cur == qcode) && (j0 + lane <= qrow));
    while (mask) {
      const int j = j0 + (__ffsll((long long)mask) - 1);
      mask &= mask - 1;
      const float* kr = Kn + (size_t)j * C + hb;
      const float* vr = V + (size_t)j * C + hb;
      const float k0v = kr[lane], k1v = kr[lane + 64];
      const float v0 = vr[lane], v1 = vr[lane + 64];
      const float s = wave_sum(q0 * k0v + q1 * k1v) * SCALE;
      const float m_new = fmaxf(m, s);
      const float alpha = __expf(m - m_new);
      const float p = __expf(s - m_new);
      l = l * alpha + p;
      acc0 = acc0 * alpha + p * v0;
      acc1 = acc1 * alpha + p * v1;
      m = m_new;
    }
  }
  const float invl = (l > 0.f) ? 1.0f / l : 0.f;
  Y[(size_t)qrow * C + hb + lane] = acc0 * invl;
  Y[(size_t)qrow * C + hb + lane + 64] = acc1 * invl;
}

extern "C" void kernel_launch(void* const* d_in, const int* in_sizes, int n_in,
                              void* d_out, int out_size, void* d_ws, size_t ws_size,
                              hipStream_t stream) {
  (void)in_sizes; (void)n_in; (void)out_size; (void)ws_size;
  const float* x     = (const float*)d_in[0];
  const float* cosb  = (const float*)d_in[1];
  const float* sinb  = (const float*)d_in[2];
  const float* Wq    = (const float*)d_in[3];
  const float* Wk    = (const float*)d_in[4];
  const float* Wv    = (const float*)d_in[5];
  const float* Wproj = (const float*)d_in[6];
  const float* Wdq   = (const float*)d_in[7];
  const float* Wdk   = (const float*)d_in[8];
  float* out = (float*)d_out;

  // ws: Kbuf 16MiB | V 16MiB | Y 16MiB | Wbf 8MiB | codes  = 56.25 MiB
  float* Kbuf = (float*)d_ws;
  float* V    = Kbuf + (size_t)T * C;
  float* Y    = V    + (size_t)T * C;
  unsigned short* Wbf = (unsigned short*)(Y + (size_t)T * C);
  int*   qc   = (int*)(Wbf + (size_t)T * C);
  int*   kc   = qc + NH * T;
  unsigned short* xbf = (unsigned short*)Y;     // x_bf lives in Y until attn
  unsigned short* Ybf = (unsigned short*)Kbuf;  // Y_bf lives in Kbuf after attn
  float* Q    = out;                 // Q dead before proj overwrites d_out

  const int n4 = T * C / 4;
  to_bf16<<<2048, 256, 0, stream>>>(x, xbf, n4);
  to_bf16<<<2048, 256, 0, stream>>>(Wv, Wbf, n4);
  gemm_bf16n<<<dim3(T / VBM, C / VBN), 256, 0, stream>>>(xbf, Wbf, V);
  gemm_qk<<<dim3(C / TM, C / TN, 2), 256, 0, stream>>>(x, Wq, Wk, Q, Kbuf);
  rope_fused<<<dim3(T * NH / 4, 2), 256, 0, stream>>>(Q, Kbuf, cosb, sinb, Wdq, Wdk, qc, kc);
  attn_sparse<<<T * NH / 4, 256, 0, stream>>>(Q, Kbuf, V, qc, kc, Y);   // overwrites xbf (dead)
  to_bf16<<<2048, 256, 0, stream>>>(Y, Ybf, n4);                        // into Kbuf (K dead)
  to_bf16<<<2048, 256, 0, stream>>>(Wproj, Wbf, n4);                    // Wv_bf dead
  gemm_bf16n<<<dim3(T / VBM, C / VBN), 256, 0, stream>>>(Ybf, Wbf, out);
}

// Round 5
// 559.376 us; speedup vs baseline: 1.3635x; 1.3635x over previous
//
#include <hip/hip_runtime.h>
#include <hip/hip_bf16.h>
#include <math.h>

#define T 2048
#define C 2048
#define NH 16
#define HD 128
#define SCALE 0.08838834764831845f   // 1/sqrt(128)
#define WL_CAP 2048
#define MARG 1e-4f                    // |sig*1.99-1| margin ~ |z-z*|<2e-4

typedef short s16x8 __attribute__((ext_vector_type(8)));
typedef float f32x4 __attribute__((ext_vector_type(4)));
typedef _Float16 f16;
typedef f16 f16x8 __attribute__((ext_vector_type(8)));

__device__ __forceinline__ float wave_sum(float v) {
  #pragma unroll
  for (int o = 32; o > 0; o >>= 1) v += __shfl_xor(v, o, 64);
  return v;
}
// RNE fp32->bf16
__device__ __forceinline__ unsigned short f2bf(float f) {
  unsigned u = __float_as_uint(f);
  u += 0x7FFFu + ((u >> 16) & 1u);
  return (unsigned short)(u >> 16);
}

// ---------------- fp32 -> bf16 pre-convert (elementwise) ----------------
__global__ __launch_bounds__(256) void to_bf16(const float* __restrict__ in,
                                               unsigned short* __restrict__ outp,
                                               int n4) {
  int i = blockIdx.x * blockDim.x + threadIdx.x;
  const int stride = gridDim.x * blockDim.x;
  for (; i < n4; i += stride) {
    float4 v = ((const float4*)in)[i];
    ushort4 o;
    o.x = f2bf(v.x); o.y = f2bf(v.y); o.z = f2bf(v.z); o.w = f2bf(v.w);
    ((ushort4*)outp)[i] = o;
  }
}

// ---------------- Q/K GEMM via RNE fp16 2-level split MFMA ----------------
// VALUES ONLY (smooth path). Codes for marginal rows are fixed by fix_codes.
// a = a2 + a1/2048 + r, |r| <= 2^-22|a|; 4 MFMA terms in 3 fp32 acc groups,
// combined L0*2^-24 + L1*2^-35 + L2*2^-46 (inputs pre-scaled by 2^12).
// Tile 64x128, BK=32, double-buffered, XOR-swizzled LDS.
#define SBM 64
#define SBN 128
#define SBK 32
#define PRESC 4096.0f               // 2^12
#define S0F 5.9604644775390625e-8f  // 2^-24
#define S1F 2.9103830456733704e-11f // 2^-35
#define S2F 1.4210854715202004e-14f // 2^-46

__device__ __forceinline__ void split8(const float4 v0, const float4 v1,
                                       uint4& hi, uint4& lo) {
  float s[8] = {v0.x * PRESC, v0.y * PRESC, v0.z * PRESC, v0.w * PRESC,
                v1.x * PRESC, v1.y * PRESC, v1.z * PRESC, v1.w * PRESC};
  union { uint4 u; f16 h[8]; } H, L;
  #pragma unroll
  for (int i = 0; i < 8; ++i) {
    f16 h2 = (f16)s[i];                 // RNE v_cvt_f16_f32
    float d = s[i] - (float)h2;         // exact (Sterbenz)
    H.h[i] = h2;
    L.h[i] = (f16)(d * 2048.0f);        // RNE; |resid| <= 2^-22|s|
  }
  hi = H.u; lo = L.u;
}

__global__ __launch_bounds__(256, 2) void gemm_qk_split16(const float* __restrict__ A,
                                                          const float* __restrict__ Wq,
                                                          const float* __restrict__ Wk,
                                                          float* __restrict__ Qo,
                                                          float* __restrict__ Ko) {
  const float* __restrict__ Bw = blockIdx.z ? Wk : Wq;
  float* __restrict__ Cc = blockIdx.z ? Ko : Qo;
  __shared__ unsigned short Ah[2][SBM * SBK];   // 2 x 4 KB
  __shared__ unsigned short Av[2][SBM * SBK];   // 2 x 4 KB (lo plane)
  __shared__ unsigned short Bh[2][SBN * SBK];   // 2 x 8 KB
  __shared__ unsigned short Bv[2][SBN * SBK];   // 2 x 8 KB  (48 KB total)
  const int tid = threadIdx.x;
  const int bm = blockIdx.x * SBM;
  const int bn = blockIdx.y * SBN;
  const int wv = tid >> 6, lane = tid & 63;
  const int wm = wv & 1, wn = wv >> 1;
  const int lrow = lane & 15, lquad = lane >> 4;

  const int a_row = tid >> 2, qg = tid & 3;
  const int a_qs = qg ^ ((a_row >> 1) & 3);
  const int b_row0 = tid >> 2;
  const int b_qs = qg ^ ((b_row0 >> 1) & 3);

  f32x4 acc[3][2][4];
  #pragma unroll
  for (int g = 0; g < 3; ++g)
    #pragma unroll
    for (int i = 0; i < 2; ++i)
      #pragma unroll
      for (int j = 0; j < 4; ++j) acc[g][i][j] = (f32x4){0.f, 0.f, 0.f, 0.f};

  {
    const float* pA  = A  + (size_t)(bm + a_row) * C + qg * 8;
    const float* pB0 = Bw + (size_t)(bn + b_row0) * C + qg * 8;
    const float* pB1 = Bw + (size_t)(bn + 64 + b_row0) * C + qg * 8;
    uint4 h, l;
    split8(*(const float4*)pA, *(const float4*)(pA + 4), h, l);
    *(uint4*)&Ah[0][a_row * SBK + a_qs * 8] = h;
    *(uint4*)&Av[0][a_row * SBK + a_qs * 8] = l;
    split8(*(const float4*)pB0, *(const float4*)(pB0 + 4), h, l);
    *(uint4*)&Bh[0][b_row0 * SBK + b_qs * 8] = h;
    *(uint4*)&Bv[0][b_row0 * SBK + b_qs * 8] = l;
    split8(*(const float4*)pB1, *(const float4*)(pB1 + 4), h, l);
    *(uint4*)&Bh[0][(64 + b_row0) * SBK + b_qs * 8] = h;
    *(uint4*)&Bv[0][(64 + b_row0) * SBK + b_qs * 8] = l;
  }
  __syncthreads();

  const int niter = C / SBK;
  for (int it = 0; it < niter; ++it) {
    const int cur = it & 1;
    const bool has = (it + 1) < niter;
    float4 a0n, a1n, b00n, b01n, b10n, b11n;
    if (has) {
      const int k0 = (it + 1) * SBK;
      const float* pA  = A  + (size_t)(bm + a_row) * C + k0 + qg * 8;
      const float* pB0 = Bw + (size_t)(bn + b_row0) * C + k0 + qg * 8;
      const float* pB1 = Bw + (size_t)(bn + 64 + b_row0) * C + k0 + qg * 8;
      a0n = *(const float4*)pA;   a1n = *(const float4*)(pA + 4);
      b00n = *(const float4*)pB0; b01n = *(const float4*)(pB0 + 4);
      b10n = *(const float4*)pB1; b11n = *(const float4*)(pB1 + 4);
    }
    f16x8 ah[2], av[2], bh[4], bv[4];
    #pragma unroll
    for (int mi = 0; mi < 2; ++mi) {
      const int r = wm * 32 + mi * 16 + lrow;
      const int q = lquad ^ ((r >> 1) & 3);
      ah[mi] = *(const f16x8*)&Ah[cur][r * SBK + q * 8];
      av[mi] = *(const f16x8*)&Av[cur][r * SBK + q * 8];
    }
    #pragma unroll
    for (int ni = 0; ni < 4; ++ni) {
      const int r = wn * 64 + ni * 16 + lrow;
      const int q = lquad ^ ((r >> 1) & 3);
      bh[ni] = *(const f16x8*)&Bh[cur][r * SBK + q * 8];
      bv[ni] = *(const f16x8*)&Bv[cur][r * SBK + q * 8];
    }
    #pragma unroll
    for (int mi = 0; mi < 2; ++mi)
      #pragma unroll
      for (int ni = 0; ni < 4; ++ni) {
        acc[0][mi][ni] = __builtin_amdgcn_mfma_f32_16x16x32_f16(ah[mi], bh[ni], acc[0][mi][ni], 0, 0, 0);
        acc[1][mi][ni] = __builtin_amdgcn_mfma_f32_16x16x32_f16(ah[mi], bv[ni], acc[1][mi][ni], 0, 0, 0);
        acc[1][mi][ni] = __builtin_amdgcn_mfma_f32_16x16x32_f16(av[mi], bh[ni], acc[1][mi][ni], 0, 0, 0);
        acc[2][mi][ni] = __builtin_amdgcn_mfma_f32_16x16x32_f16(av[mi], bv[ni], acc[2][mi][ni], 0, 0, 0);
      }
    if (has) {
      const int nxt = cur ^ 1;
      uint4 h, l;
      split8(a0n, a1n, h, l);
      *(uint4*)&Ah[nxt][a_row * SBK + a_qs * 8] = h;
      *(uint4*)&Av[nxt][a_row * SBK + a_qs * 8] = l;
      split8(b00n, b01n, h, l);
      *(uint4*)&Bh[nxt][b_row0 * SBK + b_qs * 8] = h;
      *(uint4*)&Bv[nxt][b_row0 * SBK + b_qs * 8] = l;
      split8(b10n, b11n, h, l);
      *(uint4*)&Bh[nxt][(64 + b_row0) * SBK + b_qs * 8] = h;
      *(uint4*)&Bv[nxt][(64 + b_row0) * SBK + b_qs * 8] = l;
    }
    __syncthreads();
  }
  #pragma unroll
  for (int mi = 0; mi < 2; ++mi)
    #pragma unroll
    for (int ni = 0; ni < 4; ++ni)
      #pragma unroll
      for (int r = 0; r < 4; ++r) {
        int row = bm + wm * 32 + mi * 16 + lquad * 4 + r;
        int col = bn + wn * 64 + ni * 16 + lrow;
        float v = acc[0][mi][ni][r] * S0F + (acc[1][mi][ni][r] * S1F + acc[2][mi][ni][r] * S2F);
        Cc[(size_t)row * C + col] = v;
      }
}

// ---------------- bf16 MFMA GEMM (smooth paths), pre-converted inputs ------
#define VBM 64
#define VBN 128
#define VBK 32

__global__ __launch_bounds__(256) void gemm_bf16n(const unsigned short* __restrict__ A,
                                                  const unsigned short* __restrict__ B,
                                                  float* __restrict__ Cc) {
  __shared__ unsigned short Al[2][VBM * VBK];
  __shared__ unsigned short Bl[2][VBN * VBK];
  const int tid = threadIdx.x;
  const int bm = blockIdx.x * VBM;
  const int bn = blockIdx.y * VBN;
  const int wv = tid >> 6, lane = tid & 63;
  const int wm = wv & 1, wn = wv >> 1;
  const int lrow = lane & 15, lquad = lane >> 4;

  const int a_row = tid >> 2, qg = tid & 3;
  const int a_qs = qg ^ ((a_row >> 1) & 3);
  const int b_row0 = tid >> 2;
  const int b_qs = qg ^ ((b_row0 >> 1) & 3);

  f32x4 acc[2][4];
  #pragma unroll
  for (int i = 0; i < 2; ++i)
    #pragma unroll
    for (int j = 0; j < 4; ++j) acc[i][j] = (f32x4){0.f, 0.f, 0.f, 0.f};

  {
    uint4 av = *(const uint4*)(A + (size_t)(bm + a_row) * C + qg * 8);
    uint4 b0 = *(const uint4*)(B + (size_t)(bn + b_row0) * C + qg * 8);
    uint4 b1 = *(const uint4*)(B + (size_t)(bn + 64 + b_row0) * C + qg * 8);
    *(uint4*)&Al[0][a_row * VBK + a_qs * 8] = av;
    *(uint4*)&Bl[0][b_row0 * VBK + b_qs * 8] = b0;
    *(uint4*)&Bl[0][(64 + b_row0) * VBK + b_qs * 8] = b1;
  }
  __syncthreads();

  const int niter = C / VBK;
  for (int it = 0; it < niter; ++it) {
    const int cur = it & 1;
    const bool has = (it + 1) < niter;
    uint4 avn, b0n, b1n;
    if (has) {
      const int k0 = (it + 1) * VBK;
      avn = *(const uint4*)(A + (size_t)(bm + a_row) * C + k0 + qg * 8);
      b0n = *(const uint4*)(B + (size_t)(bn + b_row0) * C + k0 + qg * 8);
      b1n = *(const uint4*)(B + (size_t)(bn + 64 + b_row0) * C + k0 + qg * 8);
    }
    s16x8 af[2], bfr[4];
    #pragma unroll
    for (int mi = 0; mi < 2; ++mi) {
      const int r = wm * 32 + mi * 16 + lrow;
      const int q = lquad ^ ((r >> 1) & 3);
      af[mi] = *(const s16x8*)&Al[cur][r * VBK + q * 8];
    }
    #pragma unroll
    for (int ni = 0; ni < 4; ++ni) {
      const int r = wn * 64 + ni * 16 + lrow;
      const int q = lquad ^ ((r >> 1) & 3);
      bfr[ni] = *(const s16x8*)&Bl[cur][r * VBK + q * 8];
    }
    #pragma unroll
    for (int mi = 0; mi < 2; ++mi)
      #pragma unroll
      for (int ni = 0; ni < 4; ++ni)
        acc[mi][ni] = __builtin_amdgcn_mfma_f32_16x16x32_bf16(af[mi], bfr[ni], acc[mi][ni], 0, 0, 0);
    if (has) {
      const int nxt = cur ^ 1;
      *(uint4*)&Al[nxt][a_row * VBK + a_qs * 8] = avn;
      *(uint4*)&Bl[nxt][b_row0 * VBK + b_qs * 8] = b0n;
      *(uint4*)&Bl[nxt][(64 + b_row0) * VBK + b_qs * 8] = b1n;
    }
    __syncthreads();
  }
  #pragma unroll
  for (int mi = 0; mi < 2; ++mi)
    #pragma unroll
    for (int ni = 0; ni < 4; ++ni)
      #pragma unroll
      for (int r = 0; r < 4; ++r) {
        int row = bm + wm * 32 + mi * 16 + lquad * 4 + r;
        int col = bn + wn * 64 + ni * 16 + lrow;
        Cc[(size_t)row * C + col] = acc[mi][ni][r];
      }
}

// ---------------- zero worklist counter ----------------
__global__ void zero_ctr(int* __restrict__ ctr) {
  if (threadIdx.x == 0) ctr[0] = 0;
}

// ---------------- RoPE + RMSNorm + bucket codes + marginal-row flagging ----
// Codes computed from MFMA Q/K values; rows where any bit's z is within
// ~2e-4 of the threshold are appended to a worklist for exact recompute.
__global__ __launch_bounds__(256) void rope_fused(float* __restrict__ Qb,
                                                  float* __restrict__ Kb,
                                                  const float* __restrict__ cosb,
                                                  const float* __restrict__ sinb,
                                                  const float* __restrict__ Wdq,
                                                  const float* __restrict__ Wdk,
                                                  int* __restrict__ qcodes,
                                                  int* __restrict__ kcodes,
                                                  int* __restrict__ wl,
                                                  int* __restrict__ ctr) {
  float* __restrict__ buf = blockIdx.y ? Kb : Qb;
  const float* __restrict__ Wd = blockIdx.y ? Wdk : Wdq;
  int* __restrict__ codes = blockIdx.y ? kcodes : qcodes;
  int wave = (blockIdx.x << 2) + (threadIdx.x >> 6);
  int lane = threadIdx.x & 63;
  int t = wave / NH, h = wave % NH;
  size_t base = (size_t)t * C + h * HD;
  float x1 = buf[base + lane];
  float x2 = buf[base + lane + 64];
  float c = cosb[t * 64 + lane];
  float s = sinb[t * 64 + lane];
  float r1 = x1 * c + x2 * s;
  float r2 = x2 * c - x1 * s;       // -x1*s + x2*c
  float ss = wave_sum(r1 * r1 + r2 * r2);
  float inv = 1.0f / sqrtf(ss * (1.0f / 128.0f) + 1e-6f);
  r1 *= inv; r2 *= inv;
  buf[base + lane] = r1;
  buf[base + lane + 64] = r2;
  int code = 0;
  bool marg = false;
  #pragma unroll
  for (int kk = 0; kk < 7; ++kk) {
    float z = r1 * Wd[kk * HD + lane] + r2 * Wd[kk * HD + lane + 64];
    z = wave_sum(z);
    float sig = 1.0f / (1.0f + expf(-z));
    float d = sig * 1.99f - 1.0f;
    if (d >= 0.f) code |= (1 << kk);
    marg |= (fabsf(d) < MARG);
  }
  if (lane == 0) {
    codes[h * T + t] = code;
    if (marg) {
      int i = atomicAdd(ctr, 1);
      if (i < WL_CAP) wl[i] = ((int)blockIdx.y << 15) | (h << 11) | t;
    }
  }
}

// ---------------- exact code recompute for marginal rows (FROZEN path) -----
// Replicates the frozen fp32 per-element GEMM sequence (k ascending, 4
// partials by k&3, pairwise merge) + frozen rope/norm/code math verbatim.
__global__ __launch_bounds__(64) void fix_codes(const float* __restrict__ x,
                                                const float* __restrict__ Wq,
                                                const float* __restrict__ Wk,
                                                const float* __restrict__ cosb,
                                                const float* __restrict__ sinb,
                                                const float* __restrict__ Wdq,
                                                const float* __restrict__ Wdk,
                                                int* __restrict__ qc,
                                                int* __restrict__ kc,
                                                const int* __restrict__ wl,
                                                const int* __restrict__ ctr) {
  const int n = min(ctr[0], WL_CAP);
  const int lane = threadIdx.x;
  for (int e = blockIdx.x; e < n; e += gridDim.x) {
    const int ent = wl[e];
    const int isK = ent >> 15;
    const int h = (ent >> 11) & 15;
    const int t = ent & 2047;
    const float* __restrict__ W  = isK ? Wk : Wq;
    const float* __restrict__ Wd = isK ? Wdk : Wdq;
    int* __restrict__ codes = isK ? kc : qc;

    const float* xr = x + (size_t)t * C;
    const float* w0 = W + (size_t)(h * HD + lane) * C;
    const float* w1 = W + (size_t)(h * HD + lane + 64) * C;
    float p0[4] = {0.f, 0.f, 0.f, 0.f};
    float p1[4] = {0.f, 0.f, 0.f, 0.f};
    for (int k = 0; k < C; k += 4) {
      float4 xv = *(const float4*)(xr + k);
      float4 a = *(const float4*)(w0 + k);
      float4 b = *(const float4*)(w1 + k);
      p0[0] += xv.x * a.x; p0[1] += xv.y * a.y;
      p0[2] += xv.z * a.z; p0[3] += xv.w * a.w;
      p1[0] += xv.x * b.x; p1[1] += xv.y * b.y;
      p1[2] += xv.z * b.z; p1[3] += xv.w * b.w;
    }
    float x1 = (p0[0] + p0[1]) + (p0[2] + p0[3]);   // frozen merge
    float x2 = (p1[0] + p1[1]) + (p1[2] + p1[3]);
    float c = cosb[t * 64 + lane];
    float s = sinb[t * 64 + lane];
    float r1 = x1 * c + x2 * s;
    float r2 = x2 * c - x1 * s;
    float ss = wave_sum(r1 * r1 + r2 * r2);
    float inv = 1.0f / sqrtf(ss * (1.0f / 128.0f) + 1e-6f);
    r1 *= inv; r2 *= inv;
    int code = 0;
    #pragma unroll
    for (int kk = 0; kk < 7; ++kk) {
      float z = r1 * Wd[kk * HD + lane] + r2 * Wd[kk * HD + lane + 64];
      z = wave_sum(z);
      float sig = 1.0f / (1.0f + expf(-z));
      if (sig * 1.99f >= 1.0f) code |= (1 << kk);
    }
    if (lane == 0) codes[h * T + t] = code;
  }
}

// ---------------- sparse ballot-scan attention (validated round 7) ---------
__global__ __launch_bounds__(256) void attn_sparse(const float* __restrict__ Q,
                                                   const float* __restrict__ Kn,
                                                   const float* __restrict__ V,
                                                   const int* __restrict__ qc,
                                                   const int* __restrict__ kc,
                                                   float* __restrict__ Y) {
  const int tid = threadIdx.x;
  const int lane = tid & 63;
  const int wave_id = blockIdx.x * 4 + (tid >> 6);   // [0, T*NH)
  const int h = wave_id & (NH - 1);
  const int qrow = wave_id >> 4;
  const size_t hb = (size_t)h * HD;

  const float q0 = Q[(size_t)qrow * C + hb + lane];
  const float q1 = Q[(size_t)qrow * C + hb + lane + 64];
  const int qcode = qc[h * T + qrow];
  const int* kch = kc + h * T;

  float m = -1e30f, l = 0.f, acc0 = 0.f, acc1 = 0.f;

  const int nchunks = (qrow >> 6) + 1;
  int kcj = kch[lane];
  for (int ci = 0; ci < nchunks; ++ci) {
    const int j0 = ci << 6;
    const int cur = kcj;
    if (ci + 1 < nchunks) kcj = kch[j0 + 64 + lane];
    unsigned long long mask = __ballot((cur == qcode) && (j0 + lane <= qrow));
    while (mask) {
      const int j = j0 + (__ffsll((long long)mask) - 1);
      mask &= mask - 1;
      const float* kr = Kn + (size_t)j * C + hb;
      const float* vr = V + (size_t)j * C + hb;
      const float k0v = kr[lane], k1v = kr[lane + 64];
      const float v0 = vr[lane], v1 = vr[lane + 64];
      const float s = wave_sum(q0 * k0v + q1 * k1v) * SCALE;
      const float m_new = fmaxf(m, s);
      const float alpha = __expf(m - m_new);
      const float p = __expf(s - m_new);
      l = l * alpha + p;
      acc0 = acc0 * alpha + p * v0;
      acc1 = acc1 * alpha + p * v1;
      m = m_new;
    }
  }
  const float invl = (l > 0.f) ? 1.0f / l : 0.f;
  Y[(size_t)qrow * C + hb + lane] = acc0 * invl;
  Y[(size_t)qrow * C + hb + lane + 64] = acc1 * invl;
}

extern "C" void kernel_launch(void* const* d_in, const int* in_sizes, int n_in,
                              void* d_out, int out_size, void* d_ws, size_t ws_size,
                              hipStream_t stream) {
  (void)in_sizes; (void)n_in; (void)out_size; (void)ws_size;
  const float* x     = (const float*)d_in[0];
  const float* cosb  = (const float*)d_in[1];
  const float* sinb  = (const float*)d_in[2];
  const float* Wq    = (const float*)d_in[3];
  const float* Wk    = (const float*)d_in[4];
  const float* Wv    = (const float*)d_in[5];
  const float* Wproj = (const float*)d_in[6];
  const float* Wdq   = (const float*)d_in[7];
  const float* Wdk   = (const float*)d_in[8];
  float* out = (float*)d_out;

  // ws: Kbuf 16MiB | V 16MiB | Y 16MiB | Wbf 8MiB | codes | ctr | wl
  float* Kbuf = (float*)d_ws;
  float* V    = Kbuf + (size_t)T * C;
  float* Y    = V    + (size_t)T * C;
  unsigned short* Wbf = (unsigned short*)(Y + (size_t)T * C);
  int*   qc   = (int*)(Wbf + (size_t)T * C);
  int*   kc   = qc + NH * T;
  int*   ctr  = kc + NH * T;
  int*   wl   = ctr + 16;
  unsigned short* xbf = (unsigned short*)Y;     // x_bf lives in Y until attn
  unsigned short* Ybf = (unsigned short*)Kbuf;  // Y_bf lives in Kbuf after attn
  float* Q    = out;                 // Q dead before proj overwrites d_out

  const int n4 = T * C / 4;
  to_bf16<<<2048, 256, 0, stream>>>(x, xbf, n4);
  to_bf16<<<2048, 256, 0, stream>>>(Wv, Wbf, n4);
  gemm_bf16n<<<dim3(T / VBM, C / VBN), 256, 0, stream>>>(xbf, Wbf, V);
  gemm_qk_split16<<<dim3(T / SBM, C / SBN, 2), 256, 0, stream>>>(x, Wq, Wk, Q, Kbuf);
  zero_ctr<<<1, 64, 0, stream>>>(ctr);
  rope_fused<<<dim3(T * NH / 4, 2), 256, 0, stream>>>(Q, Kbuf, cosb, sinb, Wdq, Wdk, qc, kc, wl, ctr);
  fix_codes<<<256, 64, 0, stream>>>(x, Wq, Wk, cosb, sinb, Wdq, Wdk, qc, kc, wl, ctr);
  attn_sparse<<<T * NH / 4, 256, 0, stream>>>(Q, Kbuf, V, qc, kc, Y);   // overwrites xbf (dead)
  to_bf16<<<2048, 256, 0, stream>>>(Y, Ybf, n4);                        // into Kbuf (K dead)
  to_bf16<<<2048, 256, 0, stream>>>(Wproj, Wbf, n4);                    // Wv_bf dead
  gemm_bf16n<<<dim3(T / VBM, C / VBN), 256, 0, stream>>>(Ybf, Wbf, out);
}

// Round 6
// 504.362 us; speedup vs baseline: 1.5123x; 1.1091x over previous
//
#include <hip/hip_runtime.h>
#include <hip/hip_bf16.h>
#include <math.h>

#define T 2048
#define C 2048
#define NH 16
#define HD 128
#define SCALE 0.08838834764831845f   // 1/sqrt(128)
#define WL_CAP 2048
#define MARG 1e-4f                    // |sig*1.99-1| margin ~ |z-z*|<2e-4

typedef short s16x8 __attribute__((ext_vector_type(8)));
typedef float f32x4 __attribute__((ext_vector_type(4)));
typedef _Float16 f16;
typedef f16 f16x8 __attribute__((ext_vector_type(8)));

__device__ __forceinline__ float wave_sum(float v) {
  #pragma unroll
  for (int o = 32; o > 0; o >>= 1) v += __shfl_xor(v, o, 64);
  return v;
}
// RNE fp32->bf16
__device__ __forceinline__ unsigned short f2bf(float f) {
  unsigned u = __float_as_uint(f);
  u += 0x7FFFu + ((u >> 16) & 1u);
  return (unsigned short)(u >> 16);
}

// ---------------- fp32 -> bf16 pre-convert (elementwise) ----------------
__global__ __launch_bounds__(256) void to_bf16(const float* __restrict__ in,
                                               unsigned short* __restrict__ outp,
                                               int n4) {
  int i = blockIdx.x * blockDim.x + threadIdx.x;
  const int stride = gridDim.x * blockDim.x;
  for (; i < n4; i += stride) {
    float4 v = ((const float4*)in)[i];
    ushort4 o;
    o.x = f2bf(v.x); o.y = f2bf(v.y); o.z = f2bf(v.z); o.w = f2bf(v.w);
    ((ushort4*)outp)[i] = o;
  }
}

// ---------------- shared split constants ----------------
#define PRESC 4096.0f               // 2^12
#define S0F 5.9604644775390625e-8f  // 2^-24
#define S1F 2.9103830456733704e-11f // 2^-35
#define S2F 1.4210854715202004e-14f // 2^-46

// ---------------- fp32 -> fp16 hi/lo plane pre-split (elementwise) --------
// s = x*2^12; hi = RNE fp16(s); lo = RNE fp16((s-hi)*2^11). |resid|<=2^-22|s|.
__global__ __launch_bounds__(256) void split_f16(const float* __restrict__ in,
                                                 unsigned short* __restrict__ hip_,
                                                 unsigned short* __restrict__ lop,
                                                 int n4) {
  int i = blockIdx.x * blockDim.x + threadIdx.x;
  const int stride = gridDim.x * blockDim.x;
  for (; i < n4; i += stride) {
    float4 v = ((const float4*)in)[i];
    float s0 = v.x * PRESC, s1 = v.y * PRESC, s2 = v.z * PRESC, s3 = v.w * PRESC;
    union { f16 h[4]; ushort4 u; } H, L;
    H.h[0] = (f16)s0; H.h[1] = (f16)s1; H.h[2] = (f16)s2; H.h[3] = (f16)s3;
    L.h[0] = (f16)((s0 - (float)H.h[0]) * 2048.0f);
    L.h[1] = (f16)((s1 - (float)H.h[1]) * 2048.0f);
    L.h[2] = (f16)((s2 - (float)H.h[2]) * 2048.0f);
    L.h[3] = (f16)((s3 - (float)H.h[3]) * 2048.0f);
    ((ushort4*)hip_)[i] = H.u;
    ((ushort4*)lop)[i] = L.u;
  }
}

#define SBM 64
#define SBN 128
#define SBK 32

// ---------------- Q/K GEMM from PRE-SPLIT fp16 planes, 3-term MFMA --------
// VALUES ONLY (smooth path); codes for marginal rows fixed by fix_codes.
// C = (hh)*2^-24 + (hl+lh)*2^-35; ll term dropped (sigma_z ~ 2.4e-7, 1000x
// below the 2e-4 flag margin). Staging is pure uint4 copies (no VALU split).
__global__ __launch_bounds__(256, 3) void gemm_qk_pre(const unsigned short* __restrict__ Ahp,
                                                      const unsigned short* __restrict__ Alp,
                                                      const unsigned short* __restrict__ Bhp,
                                                      const unsigned short* __restrict__ Blp,
                                                      float* __restrict__ Cc) {
  __shared__ unsigned short Ah[2][SBM * SBK];   // 2 x 4 KB
  __shared__ unsigned short Av[2][SBM * SBK];   // 2 x 4 KB (lo plane)
  __shared__ unsigned short Bh[2][SBN * SBK];   // 2 x 8 KB
  __shared__ unsigned short Bv[2][SBN * SBK];   // 2 x 8 KB  (48 KB total)
  const int tid = threadIdx.x;
  const int bm = blockIdx.x * SBM;
  const int bn = blockIdx.y * SBN;
  const int wv = tid >> 6, lane = tid & 63;
  const int wm = wv & 1, wn = wv >> 1;
  const int lrow = lane & 15, lquad = lane >> 4;

  const int a_row = tid >> 2, qg = tid & 3;
  const int a_qs = qg ^ ((a_row >> 1) & 3);
  const int b_row0 = tid >> 2;
  const int b_qs = qg ^ ((b_row0 >> 1) & 3);

  f32x4 acc[2][2][4];
  #pragma unroll
  for (int g = 0; g < 2; ++g)
    #pragma unroll
    for (int i = 0; i < 2; ++i)
      #pragma unroll
      for (int j = 0; j < 4; ++j) acc[g][i][j] = (f32x4){0.f, 0.f, 0.f, 0.f};

  {
    uint4 aH = *(const uint4*)(Ahp + (size_t)(bm + a_row) * C + qg * 8);
    uint4 aL = *(const uint4*)(Alp + (size_t)(bm + a_row) * C + qg * 8);
    uint4 b0H = *(const uint4*)(Bhp + (size_t)(bn + b_row0) * C + qg * 8);
    uint4 b0L = *(const uint4*)(Blp + (size_t)(bn + b_row0) * C + qg * 8);
    uint4 b1H = *(const uint4*)(Bhp + (size_t)(bn + 64 + b_row0) * C + qg * 8);
    uint4 b1L = *(const uint4*)(Blp + (size_t)(bn + 64 + b_row0) * C + qg * 8);
    *(uint4*)&Ah[0][a_row * SBK + a_qs * 8] = aH;
    *(uint4*)&Av[0][a_row * SBK + a_qs * 8] = aL;
    *(uint4*)&Bh[0][b_row0 * SBK + b_qs * 8] = b0H;
    *(uint4*)&Bv[0][b_row0 * SBK + b_qs * 8] = b0L;
    *(uint4*)&Bh[0][(64 + b_row0) * SBK + b_qs * 8] = b1H;
    *(uint4*)&Bv[0][(64 + b_row0) * SBK + b_qs * 8] = b1L;
  }
  __syncthreads();

  const int niter = C / SBK;
  for (int it = 0; it < niter; ++it) {
    const int cur = it & 1;
    const bool has = (it + 1) < niter;
    uint4 aHn, aLn, b0Hn, b0Ln, b1Hn, b1Ln;
    if (has) {
      const int k0 = (it + 1) * SBK;
      aHn = *(const uint4*)(Ahp + (size_t)(bm + a_row) * C + k0 + qg * 8);
      aLn = *(const uint4*)(Alp + (size_t)(bm + a_row) * C + k0 + qg * 8);
      b0Hn = *(const uint4*)(Bhp + (size_t)(bn + b_row0) * C + k0 + qg * 8);
      b0Ln = *(const uint4*)(Blp + (size_t)(bn + b_row0) * C + k0 + qg * 8);
      b1Hn = *(const uint4*)(Bhp + (size_t)(bn + 64 + b_row0) * C + k0 + qg * 8);
      b1Ln = *(const uint4*)(Blp + (size_t)(bn + 64 + b_row0) * C + k0 + qg * 8);
    }
    f16x8 ah[2], av[2], bh[4], bv[4];
    #pragma unroll
    for (int mi = 0; mi < 2; ++mi) {
      const int r = wm * 32 + mi * 16 + lrow;
      const int q = lquad ^ ((r >> 1) & 3);
      ah[mi] = *(const f16x8*)&Ah[cur][r * SBK + q * 8];
      av[mi] = *(const f16x8*)&Av[cur][r * SBK + q * 8];
    }
    #pragma unroll
    for (int ni = 0; ni < 4; ++ni) {
      const int r = wn * 64 + ni * 16 + lrow;
      const int q = lquad ^ ((r >> 1) & 3);
      bh[ni] = *(const f16x8*)&Bh[cur][r * SBK + q * 8];
      bv[ni] = *(const f16x8*)&Bv[cur][r * SBK + q * 8];
    }
    #pragma unroll
    for (int mi = 0; mi < 2; ++mi)
      #pragma unroll
      for (int ni = 0; ni < 4; ++ni) {
        acc[0][mi][ni] = __builtin_amdgcn_mfma_f32_16x16x32_f16(ah[mi], bh[ni], acc[0][mi][ni], 0, 0, 0);
        acc[1][mi][ni] = __builtin_amdgcn_mfma_f32_16x16x32_f16(ah[mi], bv[ni], acc[1][mi][ni], 0, 0, 0);
        acc[1][mi][ni] = __builtin_amdgcn_mfma_f32_16x16x32_f16(av[mi], bh[ni], acc[1][mi][ni], 0, 0, 0);
      }
    if (has) {
      const int nxt = cur ^ 1;
      *(uint4*)&Ah[nxt][a_row * SBK + a_qs * 8] = aHn;
      *(uint4*)&Av[nxt][a_row * SBK + a_qs * 8] = aLn;
      *(uint4*)&Bh[nxt][b_row0 * SBK + b_qs * 8] = b0Hn;
      *(uint4*)&Bv[nxt][b_row0 * SBK + b_qs * 8] = b0Ln;
      *(uint4*)&Bh[nxt][(64 + b_row0) * SBK + b_qs * 8] = b1Hn;
      *(uint4*)&Bv[nxt][(64 + b_row0) * SBK + b_qs * 8] = b1Ln;
    }
    __syncthreads();
  }
  #pragma unroll
  for (int mi = 0; mi < 2; ++mi)
    #pragma unroll
    for (int ni = 0; ni < 4; ++ni)
      #pragma unroll
      for (int r = 0; r < 4; ++r) {
        int row = bm + wm * 32 + mi * 16 + lquad * 4 + r;
        int col = bn + wn * 64 + ni * 16 + lrow;
        Cc[(size_t)row * C + col] = acc[0][mi][ni][r] * S0F + acc[1][mi][ni][r] * S1F;
      }
}

// ---------------- Q/K GEMM with IN-KERNEL split (round-5 fallback) --------
__device__ __forceinline__ void split8(const float4 v0, const float4 v1,
                                       uint4& hi, uint4& lo) {
  float s[8] = {v0.x * PRESC, v0.y * PRESC, v0.z * PRESC, v0.w * PRESC,
                v1.x * PRESC, v1.y * PRESC, v1.z * PRESC, v1.w * PRESC};
  union { uint4 u; f16 h[8]; } H, L;
  #pragma unroll
  for (int i = 0; i < 8; ++i) {
    f16 h2 = (f16)s[i];
    float d = s[i] - (float)h2;
    H.h[i] = h2;
    L.h[i] = (f16)(d * 2048.0f);
  }
  hi = H.u; lo = L.u;
}

__global__ __launch_bounds__(256, 2) void gemm_qk_split16(const float* __restrict__ A,
                                                          const float* __restrict__ Wq,
                                                          const float* __restrict__ Wk,
                                                          float* __restrict__ Qo,
                                                          float* __restrict__ Ko) {
  const float* __restrict__ Bw = blockIdx.z ? Wk : Wq;
  float* __restrict__ Cc = blockIdx.z ? Ko : Qo;
  __shared__ unsigned short Ah[2][SBM * SBK];
  __shared__ unsigned short Av[2][SBM * SBK];
  __shared__ unsigned short Bh[2][SBN * SBK];
  __shared__ unsigned short Bv[2][SBN * SBK];
  const int tid = threadIdx.x;
  const int bm = blockIdx.x * SBM;
  const int bn = blockIdx.y * SBN;
  const int wv = tid >> 6, lane = tid & 63;
  const int wm = wv & 1, wn = wv >> 1;
  const int lrow = lane & 15, lquad = lane >> 4;

  const int a_row = tid >> 2, qg = tid & 3;
  const int a_qs = qg ^ ((a_row >> 1) & 3);
  const int b_row0 = tid >> 2;
  const int b_qs = qg ^ ((b_row0 >> 1) & 3);

  f32x4 acc[3][2][4];
  #pragma unroll
  for (int g = 0; g < 3; ++g)
    #pragma unroll
    for (int i = 0; i < 2; ++i)
      #pragma unroll
      for (int j = 0; j < 4; ++j) acc[g][i][j] = (f32x4){0.f, 0.f, 0.f, 0.f};

  {
    const float* pA  = A  + (size_t)(bm + a_row) * C + qg * 8;
    const float* pB0 = Bw + (size_t)(bn + b_row0) * C + qg * 8;
    const float* pB1 = Bw + (size_t)(bn + 64 + b_row0) * C + qg * 8;
    uint4 h, l;
    split8(*(const float4*)pA, *(const float4*)(pA + 4), h, l);
    *(uint4*)&Ah[0][a_row * SBK + a_qs * 8] = h;
    *(uint4*)&Av[0][a_row * SBK + a_qs * 8] = l;
    split8(*(const float4*)pB0, *(const float4*)(pB0 + 4), h, l);
    *(uint4*)&Bh[0][b_row0 * SBK + b_qs * 8] = h;
    *(uint4*)&Bv[0][b_row0 * SBK + b_qs * 8] = l;
    split8(*(const float4*)pB1, *(const float4*)(pB1 + 4), h, l);
    *(uint4*)&Bh[0][(64 + b_row0) * SBK + b_qs * 8] = h;
    *(uint4*)&Bv[0][(64 + b_row0) * SBK + b_qs * 8] = l;
  }
  __syncthreads();

  const int niter = C / SBK;
  for (int it = 0; it < niter; ++it) {
    const int cur = it & 1;
    const bool has = (it + 1) < niter;
    float4 a0n, a1n, b00n, b01n, b10n, b11n;
    if (has) {
      const int k0 = (it + 1) * SBK;
      const float* pA  = A  + (size_t)(bm + a_row) * C + k0 + qg * 8;
      const float* pB0 = Bw + (size_t)(bn + b_row0) * C + k0 + qg * 8;
      const float* pB1 = Bw + (size_t)(bn + 64 + b_row0) * C + k0 + qg * 8;
      a0n = *(const float4*)pA;   a1n = *(const float4*)(pA + 4);
      b00n = *(const float4*)pB0; b01n = *(const float4*)(pB0 + 4);
      b10n = *(const float4*)pB1; b11n = *(const float4*)(pB1 + 4);
    }
    f16x8 ah[2], av[2], bh[4], bv[4];
    #pragma unroll
    for (int mi = 0; mi < 2; ++mi) {
      const int r = wm * 32 + mi * 16 + lrow;
      const int q = lquad ^ ((r >> 1) & 3);
      ah[mi] = *(const f16x8*)&Ah[cur][r * SBK + q * 8];
      av[mi] = *(const f16x8*)&Av[cur][r * SBK + q * 8];
    }
    #pragma unroll
    for (int ni = 0; ni < 4; ++ni) {
      const int r = wn * 64 + ni * 16 + lrow;
      const int q = lquad ^ ((r >> 1) & 3);
      bh[ni] = *(const f16x8*)&Bh[cur][r * SBK + q * 8];
      bv[ni] = *(const f16x8*)&Bv[cur][r * SBK + q * 8];
    }
    #pragma unroll
    for (int mi = 0; mi < 2; ++mi)
      #pragma unroll
      for (int ni = 0; ni < 4; ++ni) {
        acc[0][mi][ni] = __builtin_amdgcn_mfma_f32_16x16x32_f16(ah[mi], bh[ni], acc[0][mi][ni], 0, 0, 0);
        acc[1][mi][ni] = __builtin_amdgcn_mfma_f32_16x16x32_f16(ah[mi], bv[ni], acc[1][mi][ni], 0, 0, 0);
        acc[1][mi][ni] = __builtin_amdgcn_mfma_f32_16x16x32_f16(av[mi], bh[ni], acc[1][mi][ni], 0, 0, 0);
        acc[2][mi][ni] = __builtin_amdgcn_mfma_f32_16x16x32_f16(av[mi], bv[ni], acc[2][mi][ni], 0, 0, 0);
      }
    if (has) {
      const int nxt = cur ^ 1;
      uint4 h, l;
      split8(a0n, a1n, h, l);
      *(uint4*)&Ah[nxt][a_row * SBK + a_qs * 8] = h;
      *(uint4*)&Av[nxt][a_row * SBK + a_qs * 8] = l;
      split8(b00n, b01n, h, l);
      *(uint4*)&Bh[nxt][b_row0 * SBK + b_qs * 8] = h;
      *(uint4*)&Bv[nxt][b_row0 * SBK + b_qs * 8] = l;
      split8(b10n, b11n, h, l);
      *(uint4*)&Bh[nxt][(64 + b_row0) * SBK + b_qs * 8] = h;
      *(uint4*)&Bv[nxt][(64 + b_row0) * SBK + b_qs * 8] = l;
    }
    __syncthreads();
  }
  #pragma unroll
  for (int mi = 0; mi < 2; ++mi)
    #pragma unroll
    for (int ni = 0; ni < 4; ++ni)
      #pragma unroll
      for (int r = 0; r < 4; ++r) {
        int row = bm + wm * 32 + mi * 16 + lquad * 4 + r;
        int col = bn + wn * 64 + ni * 16 + lrow;
        float v = acc[0][mi][ni][r] * S0F + (acc[1][mi][ni][r] * S1F + acc[2][mi][ni][r] * S2F);
        Cc[(size_t)row * C + col] = v;
      }
}

// ---------------- bf16 MFMA GEMM (smooth paths), pre-converted inputs ------
#define VBM 64
#define VBN 128
#define VBK 32

__global__ __launch_bounds__(256) void gemm_bf16n(const unsigned short* __restrict__ A,
                                                  const unsigned short* __restrict__ B,
                                                  float* __restrict__ Cc) {
  __shared__ unsigned short Al[2][VBM * VBK];
  __shared__ unsigned short Bl[2][VBN * VBK];
  const int tid = threadIdx.x;
  const int bm = blockIdx.x * VBM;
  const int bn = blockIdx.y * VBN;
  const int wv = tid >> 6, lane = tid & 63;
  const int wm = wv & 1, wn = wv >> 1;
  const int lrow = lane & 15, lquad = lane >> 4;

  const int a_row = tid >> 2, qg = tid & 3;
  const int a_qs = qg ^ ((a_row >> 1) & 3);
  const int b_row0 = tid >> 2;
  const int b_qs = qg ^ ((b_row0 >> 1) & 3);

  f32x4 acc[2][4];
  #pragma unroll
  for (int i = 0; i < 2; ++i)
    #pragma unroll
    for (int j = 0; j < 4; ++j) acc[i][j] = (f32x4){0.f, 0.f, 0.f, 0.f};

  {
    uint4 av = *(const uint4*)(A + (size_t)(bm + a_row) * C + qg * 8);
    uint4 b0 = *(const uint4*)(B + (size_t)(bn + b_row0) * C + qg * 8);
    uint4 b1 = *(const uint4*)(B + (size_t)(bn + 64 + b_row0) * C + qg * 8);
    *(uint4*)&Al[0][a_row * VBK + a_qs * 8] = av;
    *(uint4*)&Bl[0][b_row0 * VBK + b_qs * 8] = b0;
    *(uint4*)&Bl[0][(64 + b_row0) * VBK + b_qs * 8] = b1;
  }
  __syncthreads();

  const int niter = C / VBK;
  for (int it = 0; it < niter; ++it) {
    const int cur = it & 1;
    const bool has = (it + 1) < niter;
    uint4 avn, b0n, b1n;
    if (has) {
      const int k0 = (it + 1) * VBK;
      avn = *(const uint4*)(A + (size_t)(bm + a_row) * C + k0 + qg * 8);
      b0n = *(const uint4*)(B + (size_t)(bn + b_row0) * C + k0 + qg * 8);
      b1n = *(const uint4*)(B + (size_t)(bn + 64 + b_row0) * C + k0 + qg * 8);
    }
    s16x8 af[2], bfr[4];
    #pragma unroll
    for (int mi = 0; mi < 2; ++mi) {
      const int r = wm * 32 + mi * 16 + lrow;
      const int q = lquad ^ ((r >> 1) & 3);
      af[mi] = *(const s16x8*)&Al[cur][r * VBK + q * 8];
    }
    #pragma unroll
    for (int ni = 0; ni < 4; ++ni) {
      const int r = wn * 64 + ni * 16 + lrow;
      const int q = lquad ^ ((r >> 1) & 3);
      bfr[ni] = *(const s16x8*)&Bl[cur][r * VBK + q * 8];
    }
    #pragma unroll
    for (int mi = 0; mi < 2; ++mi)
      #pragma unroll
      for (int ni = 0; ni < 4; ++ni)
        acc[mi][ni] = __builtin_amdgcn_mfma_f32_16x16x32_bf16(af[mi], bfr[ni], acc[mi][ni], 0, 0, 0);
    if (has) {
      const int nxt = cur ^ 1;
      *(uint4*)&Al[nxt][a_row * VBK + a_qs * 8] = avn;
      *(uint4*)&Bl[nxt][b_row0 * VBK + b_qs * 8] = b0n;
      *(uint4*)&Bl[nxt][(64 + b_row0) * VBK + b_qs * 8] = b1n;
    }
    __syncthreads();
  }
  #pragma unroll
  for (int mi = 0; mi < 2; ++mi)
    #pragma unroll
    for (int ni = 0; ni < 4; ++ni)
      #pragma unroll
      for (int r = 0; r < 4; ++r) {
        int row = bm + wm * 32 + mi * 16 + lquad * 4 + r;
        int col = bn + wn * 64 + ni * 16 + lrow;
        Cc[(size_t)row * C + col] = acc[mi][ni][r];
      }
}

// ---------------- zero worklist counter ----------------
__global__ void zero_ctr(int* __restrict__ ctr) {
  if (threadIdx.x == 0) ctr[0] = 0;
}

// ---------------- RoPE + RMSNorm + bucket codes + marginal-row flagging ----
__global__ __launch_bounds__(256) void rope_fused(float* __restrict__ Qb,
                                                  float* __restrict__ Kb,
                                                  const float* __restrict__ cosb,
                                                  const float* __restrict__ sinb,
                                                  const float* __restrict__ Wdq,
                                                  const float* __restrict__ Wdk,
                                                  int* __restrict__ qcodes,
                                                  int* __restrict__ kcodes,
                                                  int* __restrict__ wl,
                                                  int* __restrict__ ctr) {
  float* __restrict__ buf = blockIdx.y ? Kb : Qb;
  const float* __restrict__ Wd = blockIdx.y ? Wdk : Wdq;
  int* __restrict__ codes = blockIdx.y ? kcodes : qcodes;
  int wave = (blockIdx.x << 2) + (threadIdx.x >> 6);
  int lane = threadIdx.x & 63;
  int t = wave / NH, h = wave % NH;
  size_t base = (size_t)t * C + h * HD;
  float x1 = buf[base + lane];
  float x2 = buf[base + lane + 64];
  float c = cosb[t * 64 + lane];
  float s = sinb[t * 64 + lane];
  float r1 = x1 * c + x2 * s;
  float r2 = x2 * c - x1 * s;       // -x1*s + x2*c
  float ss = wave_sum(r1 * r1 + r2 * r2);
  float inv = 1.0f / sqrtf(ss * (1.0f / 128.0f) + 1e-6f);
  r1 *= inv; r2 *= inv;
  buf[base + lane] = r1;
  buf[base + lane + 64] = r2;
  int code = 0;
  bool marg = false;
  #pragma unroll
  for (int kk = 0; kk < 7; ++kk) {
    float z = r1 * Wd[kk * HD + lane] + r2 * Wd[kk * HD + lane + 64];
    z = wave_sum(z);
    float sig = 1.0f / (1.0f + expf(-z));
    float d = sig * 1.99f - 1.0f;
    if (d >= 0.f) code |= (1 << kk);
    marg |= (fabsf(d) < MARG);
  }
  if (lane == 0) {
    codes[h * T + t] = code;
    if (marg) {
      int i = atomicAdd(ctr, 1);
      if (i < WL_CAP) wl[i] = ((int)blockIdx.y << 15) | (h << 11) | t;
    }
  }
}

// ---------------- exact code recompute for marginal rows (FROZEN path) -----
__global__ __launch_bounds__(64) void fix_codes(const float* __restrict__ x,
                                                const float* __restrict__ Wq,
                                                const float* __restrict__ Wk,
                                                const float* __restrict__ cosb,
                                                const float* __restrict__ sinb,
                                                const float* __restrict__ Wdq,
                                                const float* __restrict__ Wdk,
                                                int* __restrict__ qc,
                                                int* __restrict__ kc,
                                                const int* __restrict__ wl,
                                                const int* __restrict__ ctr) {
  const int n = min(ctr[0], WL_CAP);
  const int lane = threadIdx.x;
  for (int e = blockIdx.x; e < n; e += gridDim.x) {
    const int ent = wl[e];
    const int isK = ent >> 15;
    const int h = (ent >> 11) & 15;
    const int t = ent & 2047;
    const float* __restrict__ W  = isK ? Wk : Wq;
    const float* __restrict__ Wd = isK ? Wdk : Wdq;
    int* __restrict__ codes = isK ? kc : qc;

    const float* xr = x + (size_t)t * C;
    const float* w0 = W + (size_t)(h * HD + lane) * C;
    const float* w1 = W + (size_t)(h * HD + lane + 64) * C;
    float p0[4] = {0.f, 0.f, 0.f, 0.f};
    float p1[4] = {0.f, 0.f, 0.f, 0.f};
    for (int k = 0; k < C; k += 4) {
      float4 xv = *(const float4*)(xr + k);
      float4 a = *(const float4*)(w0 + k);
      float4 b = *(const float4*)(w1 + k);
      p0[0] += xv.x * a.x; p0[1] += xv.y * a.y;
      p0[2] += xv.z * a.z; p0[3] += xv.w * a.w;
      p1[0] += xv.x * b.x; p1[1] += xv.y * b.y;
      p1[2] += xv.z * b.z; p1[3] += xv.w * b.w;
    }
    float x1 = (p0[0] + p0[1]) + (p0[2] + p0[3]);   // frozen merge
    float x2 = (p1[0] + p1[1]) + (p1[2] + p1[3]);
    float c = cosb[t * 64 + lane];
    float s = sinb[t * 64 + lane];
    float r1 = x1 * c + x2 * s;
    float r2 = x2 * c - x1 * s;
    float ss = wave_sum(r1 * r1 + r2 * r2);
    float inv = 1.0f / sqrtf(ss * (1.0f / 128.0f) + 1e-6f);
    r1 *= inv; r2 *= inv;
    int code = 0;
    #pragma unroll
    for (int kk = 0; kk < 7; ++kk) {
      float z = r1 * Wd[kk * HD + lane] + r2 * Wd[kk * HD + lane + 64];
      z = wave_sum(z);
      float sig = 1.0f / (1.0f + expf(-z));
      if (sig * 1.99f >= 1.0f) code |= (1 << kk);
    }
    if (lane == 0) codes[h * T + t] = code;
  }
}

// ---------------- sparse ballot-scan attention (validated round 7) ---------
__global__ __launch_bounds__(256) void attn_sparse(const float* __restrict__ Q,
                                                   const float* __restrict__ Kn,
                                                   const float* __restrict__ V,
                                                   const int* __restrict__ qc,
                                                   const int* __restrict__ kc,
                                                   float* __restrict__ Y) {
  const int tid = threadIdx.x;
  const int lane = tid & 63;
  const int wave_id = blockIdx.x * 4 + (tid >> 6);   // [0, T*NH)
  const int h = wave_id & (NH - 1);
  const int qrow = wave_id >> 4;
  const size_t hb = (size_t)h * HD;

  const float q0 = Q[(size_t)qrow * C + hb + lane];
  const float q1 = Q[(size_t)qrow * C + hb + lane + 64];
  const int qcode = qc[h * T + qrow];
  const int* kch = kc + h * T;

  float m = -1e30f, l = 0.f, acc0 = 0.f, acc1 = 0.f;

  const int nchunks = (qrow >> 6) + 1;
  int kcj = kch[lane];
  for (int ci = 0; ci < nchunks; ++ci) {
    const int j0 = ci << 6;
    const int cur = kcj;
    if (ci + 1 < nchunks) kcj = kch[j0 + 64 + lane];
    unsigned long long mask = __ballot((cur == qcode) && (j0 + lane <= qrow));
    while (mask) {
      const int j = j0 + (__ffsll((long long)mask) - 1);
      mask &= mask - 1;
      const float* kr = Kn + (size_t)j * C + hb;
      const float* vr = V + (size_t)j * C + hb;
      const float k0v = kr[lane], k1v = kr[lane + 64];
      const float v0 = vr[lane], v1 = vr[lane + 64];
      const float s = wave_sum(q0 * k0v + q1 * k1v) * SCALE;
      const float m_new = fmaxf(m, s);
      const float alpha = __expf(m - m_new);
      const float p = __expf(s - m_new);
      l = l * alpha + p;
      acc0 = acc0 * alpha + p * v0;
      acc1 = acc1 * alpha + p * v1;
      m = m_new;
    }
  }
  const float invl = (l > 0.f) ? 1.0f / l : 0.f;
  Y[(size_t)qrow * C + hb + lane] = acc0 * invl;
  Y[(size_t)qrow * C + hb + lane + 64] = acc1 * invl;
}

extern "C" void kernel_launch(void* const* d_in, const int* in_sizes, int n_in,
                              void* d_out, int out_size, void* d_ws, size_t ws_size,
                              hipStream_t stream) {
  (void)in_sizes; (void)n_in; (void)out_size;
  const float* x     = (const float*)d_in[0];
  const float* cosb  = (const float*)d_in[1];
  const float* sinb  = (const float*)d_in[2];
  const float* Wq    = (const float*)d_in[3];
  const float* Wk    = (const float*)d_in[4];
  const float* Wv    = (const float*)d_in[5];
  const float* Wproj = (const float*)d_in[6];
  const float* Wdq   = (const float*)d_in[7];
  const float* Wdk   = (const float*)d_in[8];
  float* out = (float*)d_out;

  const size_t MB = 1024 * 1024;
  char* ws = (char*)d_ws;
  float* Kbuf = (float*)ws;                       // 16 MB
  float* V    = (float*)(ws + 16 * MB);           // 16 MB
  float* Y    = (float*)(ws + 32 * MB);           // 16 MB
  unsigned short* Wbf = (unsigned short*)(ws + 48 * MB);   // 8 MB
  unsigned short* xbf = (unsigned short*)Y;       // x_bf lives in Y until attn
  unsigned short* Ybf = (unsigned short*)Kbuf;    // Y_bf lives in Kbuf after attn
  float* Q    = out;                 // Q dead before proj overwrites d_out

  const int n4 = T * C / 4;

  if (ws_size >= (size_t)64 * MB) {
    // ---- fast path: pre-split fp16 planes (64 MiB packed layout) ----
    // Y:    xbf -> xh(8MB)+xl(8MB) -> attn output
    // Kbuf: Wq planes (hi+lo) -> K output
    // Wbf:  Wv_bf -> Wk_hi -> codes -> Wproj_bf
    // +56MB: Wk_lo (8MB)
    unsigned short* xh  = (unsigned short*)Y;
    unsigned short* xl  = xh + (size_t)T * C;
    unsigned short* wqh = (unsigned short*)Kbuf;
    unsigned short* wql = wqh + (size_t)T * C;
    unsigned short* wkh = Wbf;
    unsigned short* wkl = (unsigned short*)(ws + 56 * MB);
    int* qc  = (int*)Wbf;            // written by rope AFTER wkh is dead
    int* kc  = qc + NH * T;
    int* ctr = kc + NH * T;
    int* wl  = ctr + 16;

    to_bf16<<<2048, 256, 0, stream>>>(x, xbf, n4);
    to_bf16<<<2048, 256, 0, stream>>>(Wv, Wbf, n4);
    gemm_bf16n<<<dim3(T / VBM, C / VBN), 256, 0, stream>>>(xbf, Wbf, V);
    split_f16<<<2048, 256, 0, stream>>>(x, xh, xl, n4);     // overwrites xbf (dead)
    split_f16<<<2048, 256, 0, stream>>>(Wq, wqh, wql, n4);
    split_f16<<<2048, 256, 0, stream>>>(Wk, wkh, wkl, n4);  // overwrites Wv_bf (dead)
    gemm_qk_pre<<<dim3(T / SBM, C / SBN), 256, 0, stream>>>(xh, xl, wqh, wql, Q);
    gemm_qk_pre<<<dim3(T / SBM, C / SBN), 256, 0, stream>>>(xh, xl, wkh, wkl, Kbuf); // overwrites wq planes (dead)
    zero_ctr<<<1, 64, 0, stream>>>(ctr);
    rope_fused<<<dim3(T * NH / 4, 2), 256, 0, stream>>>(Q, Kbuf, cosb, sinb, Wdq, Wdk, qc, kc, wl, ctr);
    fix_codes<<<256, 64, 0, stream>>>(x, Wq, Wk, cosb, sinb, Wdq, Wdk, qc, kc, wl, ctr);
    attn_sparse<<<T * NH / 4, 256, 0, stream>>>(Q, Kbuf, V, qc, kc, Y);  // overwrites xh/xl (dead)
    to_bf16<<<2048, 256, 0, stream>>>(Y, Ybf, n4);                       // into Kbuf (K dead)
    to_bf16<<<2048, 256, 0, stream>>>(Wproj, Wbf, n4);                   // overwrites codes (dead)
    gemm_bf16n<<<dim3(T / VBM, C / VBN), 256, 0, stream>>>(Ybf, Wbf, out);
  } else {
    // ---- fallback: round-5 proven path (56.26 MiB layout) ----
    int* qc  = (int*)(Wbf + (size_t)T * C);
    int* kc  = qc + NH * T;
    int* ctr = kc + NH * T;
    int* wl  = ctr + 16;

    to_bf16<<<2048, 256, 0, stream>>>(x, xbf, n4);
    to_bf16<<<2048, 256, 0, stream>>>(Wv, Wbf, n4);
    gemm_bf16n<<<dim3(T / VBM, C / VBN), 256, 0, stream>>>(xbf, Wbf, V);
    gemm_qk_split16<<<dim3(T / SBM, C / SBN, 2), 256, 0, stream>>>(x, Wq, Wk, Q, Kbuf);
    zero_ctr<<<1, 64, 0, stream>>>(ctr);
    rope_fused<<<dim3(T * NH / 4, 2), 256, 0, stream>>>(Q, Kbuf, cosb, sinb, Wdq, Wdk, qc, kc, wl, ctr);
    fix_codes<<<256, 64, 0, stream>>>(x, Wq, Wk, cosb, sinb, Wdq, Wdk, qc, kc, wl, ctr);
    attn_sparse<<<T * NH / 4, 256, 0, stream>>>(Q, Kbuf, V, qc, kc, Y);
    to_bf16<<<2048, 256, 0, stream>>>(Y, Ybf, n4);
    to_bf16<<<2048, 256, 0, stream>>>(Wproj, Wbf, n4);
    gemm_bf16n<<<dim3(T / VBM, C / VBN), 256, 0, stream>>>(Ybf, Wbf, out);
  }
}

// Round 7
// 502.251 us; speedup vs baseline: 1.5186x; 1.0042x over previous
//
#include <hip/hip_runtime.h>
#include <hip/hip_bf16.h>
#include <math.h>

#define T 2048
#define C 2048
#define NH 16
#define HD 128
#define SCALE 0.08838834764831845f   // 1/sqrt(128)
#define WL_CAP 2048
#define MARG 1e-4f                    // |sig*1.99-1| margin ~ |z-z*|<2e-4

typedef short s16x8 __attribute__((ext_vector_type(8)));
typedef float f32x4 __attribute__((ext_vector_type(4)));
typedef _Float16 f16;
typedef f16 f16x8 __attribute__((ext_vector_type(8)));

__device__ __forceinline__ float wave_sum(float v) {
  #pragma unroll
  for (int o = 32; o > 0; o >>= 1) v += __shfl_xor(v, o, 64);
  return v;
}
// RNE fp32->bf16
__device__ __forceinline__ unsigned short f2bf(float f) {
  unsigned u = __float_as_uint(f);
  u += 0x7FFFu + ((u >> 16) & 1u);
  return (unsigned short)(u >> 16);
}

// ---------------- fp32 -> bf16 pre-convert (fallback path only) ----------
__global__ __launch_bounds__(256) void to_bf16(const float* __restrict__ in,
                                               unsigned short* __restrict__ outp,
                                               int n4) {
  int i = blockIdx.x * blockDim.x + threadIdx.x;
  const int stride = gridDim.x * blockDim.x;
  for (; i < n4; i += stride) {
    float4 v = ((const float4*)in)[i];
    ushort4 o;
    o.x = f2bf(v.x); o.y = f2bf(v.y); o.z = f2bf(v.z); o.w = f2bf(v.w);
    ((ushort4*)outp)[i] = o;
  }
}

// ---------------- shared split constants ----------------
#define PRESC 4096.0f               // 2^12
#define S0F 5.9604644775390625e-8f  // 2^-24
#define S1F 2.9103830456733704e-11f // 2^-35
#define S2F 1.4210854715202004e-14f // 2^-46

// ---------------- fp32 -> fp16 hi/lo plane pre-split (elementwise) --------
__global__ __launch_bounds__(256) void split_f16(const float* __restrict__ in,
                                                 unsigned short* __restrict__ hip_,
                                                 unsigned short* __restrict__ lop,
                                                 int n4) {
  int i = blockIdx.x * blockDim.x + threadIdx.x;
  const int stride = gridDim.x * blockDim.x;
  for (; i < n4; i += stride) {
    float4 v = ((const float4*)in)[i];
    float s0 = v.x * PRESC, s1 = v.y * PRESC, s2 = v.z * PRESC, s3 = v.w * PRESC;
    union { f16 h[4]; ushort4 u; } H, L;
    H.h[0] = (f16)s0; H.h[1] = (f16)s1; H.h[2] = (f16)s2; H.h[3] = (f16)s3;
    L.h[0] = (f16)((s0 - (float)H.h[0]) * 2048.0f);
    L.h[1] = (f16)((s1 - (float)H.h[1]) * 2048.0f);
    L.h[2] = (f16)((s2 - (float)H.h[2]) * 2048.0f);
    L.h[3] = (f16)((s3 - (float)H.h[3]) * 2048.0f);
    ((ushort4*)hip_)[i] = H.u;
    ((ushort4*)lop)[i] = L.u;
  }
}

// ---------------- fp32 -> fp16 hi plane only (for V / proj path) ----------
__global__ __launch_bounds__(256) void to_f16h(const float* __restrict__ in,
                                               unsigned short* __restrict__ outp,
                                               int n4) {
  int i = blockIdx.x * blockDim.x + threadIdx.x;
  const int stride = gridDim.x * blockDim.x;
  for (; i < n4; i += stride) {
    float4 v = ((const float4*)in)[i];
    union { f16 h[4]; ushort4 u; } H;
    H.h[0] = (f16)(v.x * PRESC); H.h[1] = (f16)(v.y * PRESC);
    H.h[2] = (f16)(v.z * PRESC); H.h[3] = (f16)(v.w * PRESC);
    ((ushort4*)outp)[i] = H.u;
  }
}

#define SBM 64
#define SBN 128
#define SBK 32

// ---------------- fused Q+K GEMM from PRE-SPLIT fp16 planes, 3-term -------
// Body identical to the round-6 validated gemm_qk_pre; blockIdx.z selects
// (Wq,Q) vs (Wk,K). Per-element FP sequence unchanged => Q/K bit-identical.
// z-fusion doubles grid (1024 blocks) => 3 blocks/CU resident vs 2.
__global__ __launch_bounds__(256, 3) void gemm_qk2(const unsigned short* __restrict__ xhp,
                                                   const unsigned short* __restrict__ xlp,
                                                   const unsigned short* __restrict__ wqh,
                                                   const unsigned short* __restrict__ wql,
                                                   const unsigned short* __restrict__ wkh,
                                                   const unsigned short* __restrict__ wkl,
                                                   float* __restrict__ Qo,
                                                   float* __restrict__ Ko) {
  const unsigned short* __restrict__ Ahp = xhp;
  const unsigned short* __restrict__ Alp = xlp;
  const unsigned short* __restrict__ Bhp = blockIdx.z ? wkh : wqh;
  const unsigned short* __restrict__ Blp = blockIdx.z ? wkl : wql;
  float* __restrict__ Cc = blockIdx.z ? Ko : Qo;
  __shared__ unsigned short Ah[2][SBM * SBK];   // 2 x 4 KB
  __shared__ unsigned short Av[2][SBM * SBK];   // 2 x 4 KB (lo plane)
  __shared__ unsigned short Bh[2][SBN * SBK];   // 2 x 8 KB
  __shared__ unsigned short Bv[2][SBN * SBK];   // 2 x 8 KB  (48 KB total)
  const int tid = threadIdx.x;
  const int bm = blockIdx.x * SBM;
  const int bn = blockIdx.y * SBN;
  const int wv = tid >> 6, lane = tid & 63;
  const int wm = wv & 1, wn = wv >> 1;
  const int lrow = lane & 15, lquad = lane >> 4;

  const int a_row = tid >> 2, qg = tid & 3;
  const int a_qs = qg ^ ((a_row >> 1) & 3);
  const int b_row0 = tid >> 2;
  const int b_qs = qg ^ ((b_row0 >> 1) & 3);

  f32x4 acc[2][2][4];
  #pragma unroll
  for (int g = 0; g < 2; ++g)
    #pragma unroll
    for (int i = 0; i < 2; ++i)
      #pragma unroll
      for (int j = 0; j < 4; ++j) acc[g][i][j] = (f32x4){0.f, 0.f, 0.f, 0.f};

  {
    uint4 aH = *(const uint4*)(Ahp + (size_t)(bm + a_row) * C + qg * 8);
    uint4 aL = *(const uint4*)(Alp + (size_t)(bm + a_row) * C + qg * 8);
    uint4 b0H = *(const uint4*)(Bhp + (size_t)(bn + b_row0) * C + qg * 8);
    uint4 b0L = *(const uint4*)(Blp + (size_t)(bn + b_row0) * C + qg * 8);
    uint4 b1H = *(const uint4*)(Bhp + (size_t)(bn + 64 + b_row0) * C + qg * 8);
    uint4 b1L = *(const uint4*)(Blp + (size_t)(bn + 64 + b_row0) * C + qg * 8);
    *(uint4*)&Ah[0][a_row * SBK + a_qs * 8] = aH;
    *(uint4*)&Av[0][a_row * SBK + a_qs * 8] = aL;
    *(uint4*)&Bh[0][b_row0 * SBK + b_qs * 8] = b0H;
    *(uint4*)&Bv[0][b_row0 * SBK + b_qs * 8] = b0L;
    *(uint4*)&Bh[0][(64 + b_row0) * SBK + b_qs * 8] = b1H;
    *(uint4*)&Bv[0][(64 + b_row0) * SBK + b_qs * 8] = b1L;
  }
  __syncthreads();

  const int niter = C / SBK;
  for (int it = 0; it < niter; ++it) {
    const int cur = it & 1;
    const bool has = (it + 1) < niter;
    uint4 aHn, aLn, b0Hn, b0Ln, b1Hn, b1Ln;
    if (has) {
      const int k0 = (it + 1) * SBK;
      aHn = *(const uint4*)(Ahp + (size_t)(bm + a_row) * C + k0 + qg * 8);
      aLn = *(const uint4*)(Alp + (size_t)(bm + a_row) * C + k0 + qg * 8);
      b0Hn = *(const uint4*)(Bhp + (size_t)(bn + b_row0) * C + k0 + qg * 8);
      b0Ln = *(const uint4*)(Blp + (size_t)(bn + b_row0) * C + k0 + qg * 8);
      b1Hn = *(const uint4*)(Bhp + (size_t)(bn + 64 + b_row0) * C + k0 + qg * 8);
      b1Ln = *(const uint4*)(Blp + (size_t)(bn + 64 + b_row0) * C + k0 + qg * 8);
    }
    f16x8 ah[2], av[2], bh[4], bv[4];
    #pragma unroll
    for (int mi = 0; mi < 2; ++mi) {
      const int r = wm * 32 + mi * 16 + lrow;
      const int q = lquad ^ ((r >> 1) & 3);
      ah[mi] = *(const f16x8*)&Ah[cur][r * SBK + q * 8];
      av[mi] = *(const f16x8*)&Av[cur][r * SBK + q * 8];
    }
    #pragma unroll
    for (int ni = 0; ni < 4; ++ni) {
      const int r = wn * 64 + ni * 16 + lrow;
      const int q = lquad ^ ((r >> 1) & 3);
      bh[ni] = *(const f16x8*)&Bh[cur][r * SBK + q * 8];
      bv[ni] = *(const f16x8*)&Bv[cur][r * SBK + q * 8];
    }
    #pragma unroll
    for (int mi = 0; mi < 2; ++mi)
      #pragma unroll
      for (int ni = 0; ni < 4; ++ni) {
        acc[0][mi][ni] = __builtin_amdgcn_mfma_f32_16x16x32_f16(ah[mi], bh[ni], acc[0][mi][ni], 0, 0, 0);
        acc[1][mi][ni] = __builtin_amdgcn_mfma_f32_16x16x32_f16(ah[mi], bv[ni], acc[1][mi][ni], 0, 0, 0);
        acc[1][mi][ni] = __builtin_amdgcn_mfma_f32_16x16x32_f16(av[mi], bh[ni], acc[1][mi][ni], 0, 0, 0);
      }
    if (has) {
      const int nxt = cur ^ 1;
      *(uint4*)&Ah[nxt][a_row * SBK + a_qs * 8] = aHn;
      *(uint4*)&Av[nxt][a_row * SBK + a_qs * 8] = aLn;
      *(uint4*)&Bh[nxt][b_row0 * SBK + b_qs * 8] = b0Hn;
      *(uint4*)&Bv[nxt][b_row0 * SBK + b_qs * 8] = b0Ln;
      *(uint4*)&Bh[nxt][(64 + b_row0) * SBK + b_qs * 8] = b1Hn;
      *(uint4*)&Bv[nxt][(64 + b_row0) * SBK + b_qs * 8] = b1Ln;
    }
    __syncthreads();
  }
  #pragma unroll
  for (int mi = 0; mi < 2; ++mi)
    #pragma unroll
    for (int ni = 0; ni < 4; ++ni)
      #pragma unroll
      for (int r = 0; r < 4; ++r) {
        int row = bm + wm * 32 + mi * 16 + lquad * 4 + r;
        int col = bn + wn * 64 + ni * 16 + lrow;
        Cc[(size_t)row * C + col] = acc[0][mi][ni][r] * S0F + acc[1][mi][ni][r] * S1F;
      }
}

// ---------------- 1-term fp16-hi GEMM (V and proj; smooth paths) ----------
// C[m][n] = (sum_k Ah[m,k]*Bh[n,k]) * 2^-24; inputs pre-scaled by 2^12.
// fp16-hi (11 mantissa bits) is strictly more accurate than the prior bf16.
__global__ __launch_bounds__(256) void gemm_h1(const unsigned short* __restrict__ A,
                                               const unsigned short* __restrict__ B,
                                               float* __restrict__ Cc) {
  __shared__ unsigned short Ah[2][SBM * SBK];   // 2 x 4 KB
  __shared__ unsigned short Bh[2][SBN * SBK];   // 2 x 8 KB  (24 KB)
  const int tid = threadIdx.x;
  const int bm = blockIdx.x * SBM;
  const int bn = blockIdx.y * SBN;
  const int wv = tid >> 6, lane = tid & 63;
  const int wm = wv & 1, wn = wv >> 1;
  const int lrow = lane & 15, lquad = lane >> 4;

  const int a_row = tid >> 2, qg = tid & 3;
  const int a_qs = qg ^ ((a_row >> 1) & 3);
  const int b_row0 = tid >> 2;
  const int b_qs = qg ^ ((b_row0 >> 1) & 3);

  f32x4 acc[2][4];
  #pragma unroll
  for (int i = 0; i < 2; ++i)
    #pragma unroll
    for (int j = 0; j < 4; ++j) acc[i][j] = (f32x4){0.f, 0.f, 0.f, 0.f};

  {
    uint4 av = *(const uint4*)(A + (size_t)(bm + a_row) * C + qg * 8);
    uint4 b0 = *(const uint4*)(B + (size_t)(bn + b_row0) * C + qg * 8);
    uint4 b1 = *(const uint4*)(B + (size_t)(bn + 64 + b_row0) * C + qg * 8);
    *(uint4*)&Ah[0][a_row * SBK + a_qs * 8] = av;
    *(uint4*)&Bh[0][b_row0 * SBK + b_qs * 8] = b0;
    *(uint4*)&Bh[0][(64 + b_row0) * SBK + b_qs * 8] = b1;
  }
  __syncthreads();

  const int niter = C / SBK;
  for (int it = 0; it < niter; ++it) {
    const int cur = it & 1;
    const bool has = (it + 1) < niter;
    uint4 avn, b0n, b1n;
    if (has) {
      const int k0 = (it + 1) * SBK;
      avn = *(const uint4*)(A + (size_t)(bm + a_row) * C + k0 + qg * 8);
      b0n = *(const uint4*)(B + (size_t)(bn + b_row0) * C + k0 + qg * 8);
      b1n = *(const uint4*)(B + (size_t)(bn + 64 + b_row0) * C + k0 + qg * 8);
    }
    f16x8 af[2], bfr[4];
    #pragma unroll
    for (int mi = 0; mi < 2; ++mi) {
      const int r = wm * 32 + mi * 16 + lrow;
      const int q = lquad ^ ((r >> 1) & 3);
      af[mi] = *(const f16x8*)&Ah[cur][r * SBK + q * 8];
    }
    #pragma unroll
    for (int ni = 0; ni < 4; ++ni) {
      const int r = wn * 64 + ni * 16 + lrow;
      const int q = lquad ^ ((r >> 1) & 3);
      bfr[ni] = *(const f16x8*)&Bh[cur][r * SBK + q * 8];
    }
    #pragma unroll
    for (int mi = 0; mi < 2; ++mi)
      #pragma unroll
      for (int ni = 0; ni < 4; ++ni)
        acc[mi][ni] = __builtin_amdgcn_mfma_f32_16x16x32_f16(af[mi], bfr[ni], acc[mi][ni], 0, 0, 0);
    if (has) {
      const int nxt = cur ^ 1;
      *(uint4*)&Ah[nxt][a_row * SBK + a_qs * 8] = avn;
      *(uint4*)&Bh[nxt][b_row0 * SBK + b_qs * 8] = b0n;
      *(uint4*)&Bh[nxt][(64 + b_row0) * SBK + b_qs * 8] = b1n;
    }
    __syncthreads();
  }
  #pragma unroll
  for (int mi = 0; mi < 2; ++mi)
    #pragma unroll
    for (int ni = 0; ni < 4; ++ni)
      #pragma unroll
      for (int r = 0; r < 4; ++r) {
        int row = bm + wm * 32 + mi * 16 + lquad * 4 + r;
        int col = bn + wn * 64 + ni * 16 + lrow;
        Cc[(size_t)row * C + col] = acc[mi][ni][r] * S0F;
      }
}

// ---------------- Q/K GEMM with IN-KERNEL split (round-5 fallback) --------
__device__ __forceinline__ void split8(const float4 v0, const float4 v1,
                                       uint4& hi, uint4& lo) {
  float s[8] = {v0.x * PRESC, v0.y * PRESC, v0.z * PRESC, v0.w * PRESC,
                v1.x * PRESC, v1.y * PRESC, v1.z * PRESC, v1.w * PRESC};
  union { uint4 u; f16 h[8]; } H, L;
  #pragma unroll
  for (int i = 0; i < 8; ++i) {
    f16 h2 = (f16)s[i];
    float d = s[i] - (float)h2;
    H.h[i] = h2;
    L.h[i] = (f16)(d * 2048.0f);
  }
  hi = H.u; lo = L.u;
}

__global__ __launch_bounds__(256, 2) void gemm_qk_split16(const float* __restrict__ A,
                                                          const float* __restrict__ Wq,
                                                          const float* __restrict__ Wk,
                                                          float* __restrict__ Qo,
                                                          float* __restrict__ Ko) {
  const float* __restrict__ Bw = blockIdx.z ? Wk : Wq;
  float* __restrict__ Cc = blockIdx.z ? Ko : Qo;
  __shared__ unsigned short Ah[2][SBM * SBK];
  __shared__ unsigned short Av[2][SBM * SBK];
  __shared__ unsigned short Bh[2][SBN * SBK];
  __shared__ unsigned short Bv[2][SBN * SBK];
  const int tid = threadIdx.x;
  const int bm = blockIdx.x * SBM;
  const int bn = blockIdx.y * SBN;
  const int wv = tid >> 6, lane = tid & 63;
  const int wm = wv & 1, wn = wv >> 1;
  const int lrow = lane & 15, lquad = lane >> 4;

  const int a_row = tid >> 2, qg = tid & 3;
  const int a_qs = qg ^ ((a_row >> 1) & 3);
  const int b_row0 = tid >> 2;
  const int b_qs = qg ^ ((b_row0 >> 1) & 3);

  f32x4 acc[3][2][4];
  #pragma unroll
  for (int g = 0; g < 3; ++g)
    #pragma unroll
    for (int i = 0; i < 2; ++i)
      #pragma unroll
      for (int j = 0; j < 4; ++j) acc[g][i][j] = (f32x4){0.f, 0.f, 0.f, 0.f};

  {
    const float* pA  = A  + (size_t)(bm + a_row) * C + qg * 8;
    const float* pB0 = Bw + (size_t)(bn + b_row0) * C + qg * 8;
    const float* pB1 = Bw + (size_t)(bn + 64 + b_row0) * C + qg * 8;
    uint4 h, l;
    split8(*(const float4*)pA, *(const float4*)(pA + 4), h, l);
    *(uint4*)&Ah[0][a_row * SBK + a_qs * 8] = h;
    *(uint4*)&Av[0][a_row * SBK + a_qs * 8] = l;
    split8(*(const float4*)pB0, *(const float4*)(pB0 + 4), h, l);
    *(uint4*)&Bh[0][b_row0 * SBK + b_qs * 8] = h;
    *(uint4*)&Bv[0][b_row0 * SBK + b_qs * 8] = l;
    split8(*(const float4*)pB1, *(const float4*)(pB1 + 4), h, l);
    *(uint4*)&Bh[0][(64 + b_row0) * SBK + b_qs * 8] = h;
    *(uint4*)&Bv[0][(64 + b_row0) * SBK + b_qs * 8] = l;
  }
  __syncthreads();

  const int niter = C / SBK;
  for (int it = 0; it < niter; ++it) {
    const int cur = it & 1;
    const bool has = (it + 1) < niter;
    float4 a0n, a1n, b00n, b01n, b10n, b11n;
    if (has) {
      const int k0 = (it + 1) * SBK;
      const float* pA  = A  + (size_t)(bm + a_row) * C + k0 + qg * 8;
      const float* pB0 = Bw + (size_t)(bn + b_row0) * C + k0 + qg * 8;
      const float* pB1 = Bw + (size_t)(bn + 64 + b_row0) * C + k0 + qg * 8;
      a0n = *(const float4*)pA;   a1n = *(const float4*)(pA + 4);
      b00n = *(const float4*)pB0; b01n = *(const float4*)(pB0 + 4);
      b10n = *(const float4*)pB1; b11n = *(const float4*)(pB1 + 4);
    }
    f16x8 ah[2], av[2], bh[4], bv[4];
    #pragma unroll
    for (int mi = 0; mi < 2; ++mi) {
      const int r = wm * 32 + mi * 16 + lrow;
      const int q = lquad ^ ((r >> 1) & 3);
      ah[mi] = *(const f16x8*)&Ah[cur][r * SBK + q * 8];
      av[mi] = *(const f16x8*)&Av[cur][r * SBK + q * 8];
    }
    #pragma unroll
    for (int ni = 0; ni < 4; ++ni) {
      const int r = wn * 64 + ni * 16 + lrow;
      const int q = lquad ^ ((r >> 1) & 3);
      bh[ni] = *(const f16x8*)&Bh[cur][r * SBK + q * 8];
      bv[ni] = *(const f16x8*)&Bv[cur][r * SBK + q * 8];
    }
    #pragma unroll
    for (int mi = 0; mi < 2; ++mi)
      #pragma unroll
      for (int ni = 0; ni < 4; ++ni) {
        acc[0][mi][ni] = __builtin_amdgcn_mfma_f32_16x16x32_f16(ah[mi], bh[ni], acc[0][mi][ni], 0, 0, 0);
        acc[1][mi][ni] = __builtin_amdgcn_mfma_f32_16x16x32_f16(ah[mi], bv[ni], acc[1][mi][ni], 0, 0, 0);
        acc[1][mi][ni] = __builtin_amdgcn_mfma_f32_16x16x32_f16(av[mi], bh[ni], acc[1][mi][ni], 0, 0, 0);
        acc[2][mi][ni] = __builtin_amdgcn_mfma_f32_16x16x32_f16(av[mi], bv[ni], acc[2][mi][ni], 0, 0, 0);
      }
    if (has) {
      const int nxt = cur ^ 1;
      uint4 h, l;
      split8(a0n, a1n, h, l);
      *(uint4*)&Ah[nxt][a_row * SBK + a_qs * 8] = h;
      *(uint4*)&Av[nxt][a_row * SBK + a_qs * 8] = l;
      split8(b00n, b01n, h, l);
      *(uint4*)&Bh[nxt][b_row0 * SBK + b_qs * 8] = h;
      *(uint4*)&Bv[nxt][b_row0 * SBK + b_qs * 8] = l;
      split8(b10n, b11n, h, l);
      *(uint4*)&Bh[nxt][(64 + b_row0) * SBK + b_qs * 8] = h;
      *(uint4*)&Bv[nxt][(64 + b_row0) * SBK + b_qs * 8] = l;
    }
    __syncthreads();
  }
  #pragma unroll
  for (int mi = 0; mi < 2; ++mi)
    #pragma unroll
    for (int ni = 0; ni < 4; ++ni)
      #pragma unroll
      for (int r = 0; r < 4; ++r) {
        int row = bm + wm * 32 + mi * 16 + lquad * 4 + r;
        int col = bn + wn * 64 + ni * 16 + lrow;
        float v = acc[0][mi][ni][r] * S0F + (acc[1][mi][ni][r] * S1F + acc[2][mi][ni][r] * S2F);
        Cc[(size_t)row * C + col] = v;
      }
}

// ---------------- bf16 MFMA GEMM (fallback path only) ---------------------
#define VBM 64
#define VBN 128
#define VBK 32

__global__ __launch_bounds__(256) void gemm_bf16n(const unsigned short* __restrict__ A,
                                                  const unsigned short* __restrict__ B,
                                                  float* __restrict__ Cc) {
  __shared__ unsigned short Al[2][VBM * VBK];
  __shared__ unsigned short Bl[2][VBN * VBK];
  const int tid = threadIdx.x;
  const int bm = blockIdx.x * VBM;
  const int bn = blockIdx.y * VBN;
  const int wv = tid >> 6, lane = tid & 63;
  const int wm = wv & 1, wn = wv >> 1;
  const int lrow = lane & 15, lquad = lane >> 4;

  const int a_row = tid >> 2, qg = tid & 3;
  const int a_qs = qg ^ ((a_row >> 1) & 3);
  const int b_row0 = tid >> 2;
  const int b_qs = qg ^ ((b_row0 >> 1) & 3);

  f32x4 acc[2][4];
  #pragma unroll
  for (int i = 0; i < 2; ++i)
    #pragma unroll
    for (int j = 0; j < 4; ++j) acc[i][j] = (f32x4){0.f, 0.f, 0.f, 0.f};

  {
    uint4 av = *(const uint4*)(A + (size_t)(bm + a_row) * C + qg * 8);
    uint4 b0 = *(const uint4*)(B + (size_t)(bn + b_row0) * C + qg * 8);
    uint4 b1 = *(const uint4*)(B + (size_t)(bn + 64 + b_row0) * C + qg * 8);
    *(uint4*)&Al[0][a_row * VBK + a_qs * 8] = av;
    *(uint4*)&Bl[0][b_row0 * VBK + b_qs * 8] = b0;
    *(uint4*)&Bl[0][(64 + b_row0) * VBK + b_qs * 8] = b1;
  }
  __syncthreads();

  const int niter = C / VBK;
  for (int it = 0; it < niter; ++it) {
    const int cur = it & 1;
    const bool has = (it + 1) < niter;
    uint4 avn, b0n, b1n;
    if (has) {
      const int k0 = (it + 1) * VBK;
      avn = *(const uint4*)(A + (size_t)(bm + a_row) * C + k0 + qg * 8);
      b0n = *(const uint4*)(B + (size_t)(bn + b_row0) * C + k0 + qg * 8);
      b1n = *(const uint4*)(B + (size_t)(bn + 64 + b_row0) * C + k0 + qg * 8);
    }
    s16x8 af[2], bfr[4];
    #pragma unroll
    for (int mi = 0; mi < 2; ++mi) {
      const int r = wm * 32 + mi * 16 + lrow;
      const int q = lquad ^ ((r >> 1) & 3);
      af[mi] = *(const s16x8*)&Al[cur][r * VBK + q * 8];
    }
    #pragma unroll
    for (int ni = 0; ni < 4; ++ni) {
      const int r = wn * 64 + ni * 16 + lrow;
      const int q = lquad ^ ((r >> 1) & 3);
      bfr[ni] = *(const s16x8*)&Bl[cur][r * VBK + q * 8];
    }
    #pragma unroll
    for (int mi = 0; mi < 2; ++mi)
      #pragma unroll
      for (int ni = 0; ni < 4; ++ni)
        acc[mi][ni] = __builtin_amdgcn_mfma_f32_16x16x32_bf16(af[mi], bfr[ni], acc[mi][ni], 0, 0, 0);
    if (has) {
      const int nxt = cur ^ 1;
      *(uint4*)&Al[nxt][a_row * VBK + a_qs * 8] = avn;
      *(uint4*)&Bl[nxt][b_row0 * VBK + b_qs * 8] = b0n;
      *(uint4*)&Bl[nxt][(64 + b_row0) * VBK + b_qs * 8] = b1n;
    }
    __syncthreads();
  }
  #pragma unroll
  for (int mi = 0; mi < 2; ++mi)
    #pragma unroll
    for (int ni = 0; ni < 4; ++ni)
      #pragma unroll
      for (int r = 0; r < 4; ++r) {
        int row = bm + wm * 32 + mi * 16 + lquad * 4 + r;
        int col = bn + wn * 64 + ni * 16 + lrow;
        Cc[(size_t)row * C + col] = acc[mi][ni][r];
      }
}

// ---------------- zero worklist counter ----------------
__global__ void zero_ctr(int* __restrict__ ctr) {
  if (threadIdx.x == 0) ctr[0] = 0;
}

// ---------------- RoPE + RMSNorm + bucket codes + marginal-row flagging ----
__global__ __launch_bounds__(256) void rope_fused(float* __restrict__ Qb,
                                                  float* __restrict__ Kb,
                                                  const float* __restrict__ cosb,
                                                  const float* __restrict__ sinb,
                                                  const float* __restrict__ Wdq,
                                                  const float* __restrict__ Wdk,
                                                  int* __restrict__ qcodes,
                                                  int* __restrict__ kcodes,
                                                  int* __restrict__ wl,
                                                  int* __restrict__ ctr) {
  float* __restrict__ buf = blockIdx.y ? Kb : Qb;
  const float* __restrict__ Wd = blockIdx.y ? Wdk : Wdq;
  int* __restrict__ codes = blockIdx.y ? kcodes : qcodes;
  int wave = (blockIdx.x << 2) + (threadIdx.x >> 6);
  int lane = threadIdx.x & 63;
  int t = wave / NH, h = wave % NH;
  size_t base = (size_t)t * C + h * HD;
  float x1 = buf[base + lane];
  float x2 = buf[base + lane + 64];
  float c = cosb[t * 64 + lane];
  float s = sinb[t * 64 + lane];
  float r1 = x1 * c + x2 * s;
  float r2 = x2 * c - x1 * s;       // -x1*s + x2*c
  float ss = wave_sum(r1 * r1 + r2 * r2);
  float inv = 1.0f / sqrtf(ss * (1.0f / 128.0f) + 1e-6f);
  r1 *= inv; r2 *= inv;
  buf[base + lane] = r1;
  buf[base + lane + 64] = r2;
  int code = 0;
  bool marg = false;
  #pragma unroll
  for (int kk = 0; kk < 7; ++kk) {
    float z = r1 * Wd[kk * HD + lane] + r2 * Wd[kk * HD + lane + 64];
    z = wave_sum(z);
    float sig = 1.0f / (1.0f + expf(-z));
    float d = sig * 1.99f - 1.0f;
    if (d >= 0.f) code |= (1 << kk);
    marg |= (fabsf(d) < MARG);
  }
  if (lane == 0) {
    codes[h * T + t] = code;
    if (marg) {
      int i = atomicAdd(ctr, 1);
      if (i < WL_CAP) wl[i] = ((int)blockIdx.y << 15) | (h << 11) | t;
    }
  }
}

// ---------------- exact code recompute for marginal rows (FROZEN path) -----
__global__ __launch_bounds__(64) void fix_codes(const float* __restrict__ x,
                                                const float* __restrict__ Wq,
                                                const float* __restrict__ Wk,
                                                const float* __restrict__ cosb,
                                                const float* __restrict__ sinb,
                                                const float* __restrict__ Wdq,
                                                const float* __restrict__ Wdk,
                                                int* __restrict__ qc,
                                                int* __restrict__ kc,
                                                const int* __restrict__ wl,
                                                const int* __restrict__ ctr) {
  const int n = min(ctr[0], WL_CAP);
  const int lane = threadIdx.x;
  for (int e = blockIdx.x; e < n; e += gridDim.x) {
    const int ent = wl[e];
    const int isK = ent >> 15;
    const int h = (ent >> 11) & 15;
    const int t = ent & 2047;
    const float* __restrict__ W  = isK ? Wk : Wq;
    const float* __restrict__ Wd = isK ? Wdk : Wdq;
    int* __restrict__ codes = isK ? kc : qc;

    const float* xr = x + (size_t)t * C;
    const float* w0 = W + (size_t)(h * HD + lane) * C;
    const float* w1 = W + (size_t)(h * HD + lane + 64) * C;
    float p0[4] = {0.f, 0.f, 0.f, 0.f};
    float p1[4] = {0.f, 0.f, 0.f, 0.f};
    for (int k = 0; k < C; k += 4) {
      float4 xv = *(const float4*)(xr + k);
      float4 a = *(const float4*)(w0 + k);
      float4 b = *(const float4*)(w1 + k);
      p0[0] += xv.x * a.x; p0[1] += xv.y * a.y;
      p0[2] += xv.z * a.z; p0[3] += xv.w * a.w;
      p1[0] += xv.x * b.x; p1[1] += xv.y * b.y;
      p1[2] += xv.z * b.z; p1[3] += xv.w * b.w;
    }
    float x1 = (p0[0] + p0[1]) + (p0[2] + p0[3]);   // frozen merge
    float x2 = (p1[0] + p1[1]) + (p1[2] + p1[3]);
    float c = cosb[t * 64 + lane];
    float s = sinb[t * 64 + lane];
    float r1 = x1 * c + x2 * s;
    float r2 = x2 * c - x1 * s;
    float ss = wave_sum(r1 * r1 + r2 * r2);
    float inv = 1.0f / sqrtf(ss * (1.0f / 128.0f) + 1e-6f);
    r1 *= inv; r2 *= inv;
    int code = 0;
    #pragma unroll
    for (int kk = 0; kk < 7; ++kk) {
      float z = r1 * Wd[kk * HD + lane] + r2 * Wd[kk * HD + lane + 64];
      z = wave_sum(z);
      float sig = 1.0f / (1.0f + expf(-z));
      if (sig * 1.99f >= 1.0f) code |= (1 << kk);
    }
    if (lane == 0) codes[h * T + t] = code;
  }
}

// ---------------- sparse ballot-scan attention (validated) ---------------
__global__ __launch_bounds__(256) void attn_sparse(const float* __restrict__ Q,
                                                   const float* __restrict__ Kn,
                                                   const float* __restrict__ V,
                                                   const int* __restrict__ qc,
                                                   const int* __restrict__ kc,
                                                   float* __restrict__ Y) {
  const int tid = threadIdx.x;
  const int lane = tid & 63;
  const int wave_id = blockIdx.x * 4 + (tid >> 6);   // [0, T*NH)
  const int h = wave_id & (NH - 1);
  const int qrow = wave_id >> 4;
  const size_t hb = (size_t)h * HD;

  const float q0 = Q[(size_t)qrow * C + hb + lane];
  const float q1 = Q[(size_t)qrow * C + hb + lane + 64];
  const int qcode = qc[h * T + qrow];
  const int* kch = kc + h * T;

  float m = -1e30f, l = 0.f, acc0 = 0.f, acc1 = 0.f;

  const int nchunks = (qrow >> 6) + 1;
  int kcj = kch[lane];
  for (int ci = 0; ci < nchunks; ++ci) {
    const int j0 = ci << 6;
    const int cur = kcj;
    if (ci + 1 < nchunks) kcj = kch[j0 + 64 + lane];
    unsigned long long mask = __ballot((cur == qcode) && (j0 + lane <= qrow));
    while (mask) {
      const int j = j0 + (__ffsll((long long)mask) - 1);
      mask &= mask - 1;
      const float* kr = Kn + (size_t)j * C + hb;
      const float* vr = V + (size_t)j * C + hb;
      const float k0v = kr[lane], k1v = kr[lane + 64];
      const float v0 = vr[lane], v1 = vr[lane + 64];
      const float s = wave_sum(q0 * k0v + q1 * k1v) * SCALE;
      const float m_new = fmaxf(m, s);
      const float alpha = __expf(m - m_new);
      const float p = __expf(s - m_new);
      l = l * alpha + p;
      acc0 = acc0 * alpha + p * v0;
      acc1 = acc1 * alpha + p * v1;
      m = m_new;
    }
  }
  const float invl = (l > 0.f) ? 1.0f / l : 0.f;
  Y[(size_t)qrow * C + hb + lane] = acc0 * invl;
  Y[(size_t)qrow * C + hb + lane + 64] = acc1 * invl;
}

extern "C" void kernel_launch(void* const* d_in, const int* in_sizes, int n_in,
                              void* d_out, int out_size, void* d_ws, size_t ws_size,
                              hipStream_t stream) {
  (void)in_sizes; (void)n_in; (void)out_size;
  const float* x     = (const float*)d_in[0];
  const float* cosb  = (const float*)d_in[1];
  const float* sinb  = (const float*)d_in[2];
  const float* Wq    = (const float*)d_in[3];
  const float* Wk    = (const float*)d_in[4];
  const float* Wv    = (const float*)d_in[5];
  const float* Wproj = (const float*)d_in[6];
  const float* Wdq   = (const float*)d_in[7];
  const float* Wdk   = (const float*)d_in[8];
  float* out = (float*)d_out;

  const size_t MB = 1024 * 1024;
  char* ws = (char*)d_ws;
  const int n4 = T * C / 4;

  if (ws_size >= (size_t)64 * MB) {
    // ---- fast path, 64 MiB packed layout with liveness-audited reuse ----
    // [0-8)   xh      -> Y[0-16) (after V gemm)
    // [8-16)  xl      -> (Y upper half)
    // [16-24) wqh     -> wvh (after QK) -> yh (after attn)
    // [24-32) wql     -> V[24-40) lower (after QK) -> wph (after attn)
    // [32-40) wkh     -> V upper
    // [40-48) wkl     -> codes: qc | kc | ctr | wl (after QK)
    // [48-64) K
    unsigned short* xh  = (unsigned short*)(ws);
    unsigned short* xl  = (unsigned short*)(ws + 8 * MB);
    unsigned short* wqh = (unsigned short*)(ws + 16 * MB);
    unsigned short* wql = (unsigned short*)(ws + 24 * MB);
    unsigned short* wkh = (unsigned short*)(ws + 32 * MB);
    unsigned short* wkl = (unsigned short*)(ws + 40 * MB);
    float* K = (float*)(ws + 48 * MB);
    unsigned short* wvh = (unsigned short*)(ws + 16 * MB);   // after QK gemm
    float* V = (float*)(ws + 24 * MB);                        // after QK gemm
    int* qc  = (int*)(ws + 40 * MB);                          // after QK gemm
    int* kc  = qc + NH * T;
    int* ctr = kc + NH * T;
    int* wl  = ctr + 16;
    float* Y = (float*)(ws);                                  // after V gemm
    unsigned short* yh  = (unsigned short*)(ws + 16 * MB);    // after attn
    unsigned short* wph = (unsigned short*)(ws + 24 * MB);    // after attn
    float* Q = out;                 // Q dead before proj overwrites d_out

    split_f16<<<2048, 256, 0, stream>>>(x, xh, xl, n4);
    split_f16<<<2048, 256, 0, stream>>>(Wq, wqh, wql, n4);
    split_f16<<<2048, 256, 0, stream>>>(Wk, wkh, wkl, n4);
    gemm_qk2<<<dim3(T / SBM, C / SBN, 2), 256, 0, stream>>>(xh, xl, wqh, wql, wkh, wkl, Q, K);
    to_f16h<<<2048, 256, 0, stream>>>(Wv, wvh, n4);           // wqh dead
    gemm_h1<<<dim3(T / SBM, C / SBN), 256, 0, stream>>>(xh, wvh, V);  // wql/wkh dead
    zero_ctr<<<1, 64, 0, stream>>>(ctr);                      // wkl dead
    rope_fused<<<dim3(T * NH / 4, 2), 256, 0, stream>>>(Q, K, cosb, sinb, Wdq, Wdk, qc, kc, wl, ctr);
    fix_codes<<<256, 64, 0, stream>>>(x, Wq, Wk, cosb, sinb, Wdq, Wdk, qc, kc, wl, ctr);
    attn_sparse<<<T * NH / 4, 256, 0, stream>>>(Q, K, V, qc, kc, Y);  // xh/xl dead
    to_f16h<<<2048, 256, 0, stream>>>(Y, yh, n4);             // wvh dead
    to_f16h<<<2048, 256, 0, stream>>>(Wproj, wph, n4);        // V dead
    gemm_h1<<<dim3(T / SBM, C / SBN), 256, 0, stream>>>(yh, wph, out);
  } else {
    // ---- fallback: round-5 proven path (56.26 MiB layout) ----
    float* Kbuf = (float*)ws;
    float* V    = (float*)(ws + 16 * MB);
    float* Y    = (float*)(ws + 32 * MB);
    unsigned short* Wbf = (unsigned short*)(ws + 48 * MB);
    unsigned short* xbf = (unsigned short*)Y;
    unsigned short* Ybf = (unsigned short*)Kbuf;
    float* Q    = out;
    int* qc  = (int*)(Wbf + (size_t)T * C);
    int* kc  = qc + NH * T;
    int* ctr = kc + NH * T;
    int* wl  = ctr + 16;

    to_bf16<<<2048, 256, 0, stream>>>(x, xbf, n4);
    to_bf16<<<2048, 256, 0, stream>>>(Wv, Wbf, n4);
    gemm_bf16n<<<dim3(T / VBM, C / VBN), 256, 0, stream>>>(xbf, Wbf, V);
    gemm_qk_split16<<<dim3(T / SBM, C / SBN, 2), 256, 0, stream>>>(x, Wq, Wk, Q, Kbuf);
    zero_ctr<<<1, 64, 0, stream>>>(ctr);
    rope_fused<<<dim3(T * NH / 4, 2), 256, 0, stream>>>(Q, Kbuf, cosb, sinb, Wdq, Wdk, qc, kc, wl, ctr);
    fix_codes<<<256, 64, 0, stream>>>(x, Wq, Wk, cosb, sinb, Wdq, Wdk, qc, kc, wl, ctr);
    attn_sparse<<<T * NH / 4, 256, 0, stream>>>(Q, Kbuf, V, qc, kc, Y);
    to_bf16<<<2048, 256, 0, stream>>>(Y, Ybf, n4);
    to_bf16<<<2048, 256, 0, stream>>>(Wproj, Wbf, n4);
    gemm_bf16n<<<dim3(T / VBM, C / VBN), 256, 0, stream>>>(Ybf, Wbf, out);
  }
}

// Round 9
// 461.267 us; speedup vs baseline: 1.6536x; 1.0889x over previous
//
#include <hip/hip_runtime.h>
#include <hip/hip_bf16.h>
#include <math.h>

#define T 2048
#define C 2048
#define NH 16
#define HD 128
#define SCALE 0.08838834764831845f   // 1/sqrt(128)
#define WL_CAP 2048
#define MARG 1e-4f                    // |sig*1.99-1| margin ~ |z-z*|<2e-4

typedef short s16x8 __attribute__((ext_vector_type(8)));
typedef float f32x4 __attribute__((ext_vector_type(4)));
typedef _Float16 f16;
typedef f16 f16x8 __attribute__((ext_vector_type(8)));

__device__ __forceinline__ float wave_sum(float v) {
  #pragma unroll
  for (int o = 32; o > 0; o >>= 1) v += __shfl_xor(v, o, 64);
  return v;
}
// RNE fp32->bf16
__device__ __forceinline__ unsigned short f2bf(float f) {
  unsigned u = __float_as_uint(f);
  u += 0x7FFFu + ((u >> 16) & 1u);
  return (unsigned short)(u >> 16);
}

// ---------------- fp32 -> bf16 pre-convert (fallback path only) ----------
__global__ __launch_bounds__(256) void to_bf16(const float* __restrict__ in,
                                               unsigned short* __restrict__ outp,
                                               int n4) {
  int i = blockIdx.x * blockDim.x + threadIdx.x;
  const int stride = gridDim.x * blockDim.x;
  for (; i < n4; i += stride) {
    float4 v = ((const float4*)in)[i];
    ushort4 o;
    o.x = f2bf(v.x); o.y = f2bf(v.y); o.z = f2bf(v.z); o.w = f2bf(v.w);
    ((ushort4*)outp)[i] = o;
  }
}

// ---------------- shared split constants ----------------
#define PRESC 4096.0f               // 2^12
#define S0F 5.9604644775390625e-8f  // 2^-24
#define S1F 2.9103830456733704e-11f // 2^-35
#define S2F 1.4210854715202004e-14f // 2^-46

__device__ __forceinline__ void split4(float4 v, ushort4& hi, ushort4& lo) {
  float s0 = v.x * PRESC, s1 = v.y * PRESC, s2 = v.z * PRESC, s3 = v.w * PRESC;
  union { f16 h[4]; ushort4 u; } H, L;
  H.h[0] = (f16)s0; H.h[1] = (f16)s1; H.h[2] = (f16)s2; H.h[3] = (f16)s3;
  L.h[0] = (f16)((s0 - (float)H.h[0]) * 2048.0f);
  L.h[1] = (f16)((s1 - (float)H.h[1]) * 2048.0f);
  L.h[2] = (f16)((s2 - (float)H.h[2]) * 2048.0f);
  L.h[3] = (f16)((s3 - (float)H.h[3]) * 2048.0f);
  hi = H.u; lo = L.u;
}

// ---------------- fp32 -> fp16 hi/lo pre-split (fallback single) ----------
__global__ __launch_bounds__(256) void split_f16(const float* __restrict__ in,
                                                 unsigned short* __restrict__ hip_,
                                                 unsigned short* __restrict__ lop,
                                                 int n4) {
  int i = blockIdx.x * blockDim.x + threadIdx.x;
  const int stride = gridDim.x * blockDim.x;
  for (; i < n4; i += stride) {
    ushort4 h, l;
    split4(((const float4*)in)[i], h, l);
    ((ushort4*)hip_)[i] = h;
    ((ushort4*)lop)[i] = l;
  }
}

// ---------------- fused pre-split of x, Wq, Wk (1 launch) -----------------
// NOTE: does NOT touch ctr — ctr lives inside the wkl region and must be
// zeroed AFTER this kernel completes (separate zero_ctr launch).
__global__ __launch_bounds__(256) void pre_split3(const float* __restrict__ x,
                                                  const float* __restrict__ Wq,
                                                  const float* __restrict__ Wk,
                                                  unsigned short* __restrict__ xh,
                                                  unsigned short* __restrict__ xl,
                                                  unsigned short* __restrict__ wqh,
                                                  unsigned short* __restrict__ wql,
                                                  unsigned short* __restrict__ wkh,
                                                  unsigned short* __restrict__ wkl,
                                                  int n4) {
  const float* __restrict__ in;
  unsigned short *oh, *ol;
  if (blockIdx.y == 0)      { in = x;  oh = xh;  ol = xl;  }
  else if (blockIdx.y == 1) { in = Wq; oh = wqh; ol = wql; }
  else                      { in = Wk; oh = wkh; ol = wkl; }
  int i = blockIdx.x * blockDim.x + threadIdx.x;
  const int stride = gridDim.x * blockDim.x;
  for (; i < n4; i += stride) {
    ushort4 h, l;
    split4(((const float4*)in)[i], h, l);
    ((ushort4*)oh)[i] = h;
    ((ushort4*)ol)[i] = l;
  }
}

// ---------------- fp32 -> fp16 hi plane only ----------
__global__ __launch_bounds__(256) void to_f16h(const float* __restrict__ in,
                                               unsigned short* __restrict__ outp,
                                               int n4) {
  int i = blockIdx.x * blockDim.x + threadIdx.x;
  const int stride = gridDim.x * blockDim.x;
  for (; i < n4; i += stride) {
    float4 v = ((const float4*)in)[i];
    union { f16 h[4]; ushort4 u; } H;
    H.h[0] = (f16)(v.x * PRESC); H.h[1] = (f16)(v.y * PRESC);
    H.h[2] = (f16)(v.z * PRESC); H.h[3] = (f16)(v.w * PRESC);
    ((ushort4*)outp)[i] = H.u;
  }
}

// ---------------- fused tail convert: Y and Wproj to fp16-hi --------------
__global__ __launch_bounds__(256) void post_h2(const float* __restrict__ Y,
                                               const float* __restrict__ Wproj,
                                               unsigned short* __restrict__ yh,
                                               unsigned short* __restrict__ wph,
                                               int n4) {
  const float* __restrict__ in = blockIdx.y ? Wproj : Y;
  unsigned short* __restrict__ outp = blockIdx.y ? wph : yh;
  int i = blockIdx.x * blockDim.x + threadIdx.x;
  const int stride = gridDim.x * blockDim.x;
  for (; i < n4; i += stride) {
    float4 v = ((const float4*)in)[i];
    union { f16 h[4]; ushort4 u; } H;
    H.h[0] = (f16)(v.x * PRESC); H.h[1] = (f16)(v.y * PRESC);
    H.h[2] = (f16)(v.z * PRESC); H.h[3] = (f16)(v.w * PRESC);
    ((ushort4*)outp)[i] = H.u;
  }
}

#define SBM 64
#define SBN 128
#define SBK 32

// ---------------- fused Q+K GEMM, 128x(64|64) tile, A shared --------------
// B-tile = [64 cols of Wq | 64 cols of Wk]; waves (wm in M) x (wn: 0=Q,1=K),
// each 64x64 out (mi=ni=4). Per-element FP sequence identical to the
// validated gemm_qk2 (same fragments, same hh->acc0 / hl,lh->acc1 order,
// same final combine) => Q/K bit-identical. 48 MFMA per 24 LDS ops per wave.
__global__ __launch_bounds__(256, 2) void gemm_qkf(const unsigned short* __restrict__ xhp,
                                                   const unsigned short* __restrict__ xlp,
                                                   const unsigned short* __restrict__ wqh,
                                                   const unsigned short* __restrict__ wql,
                                                   const unsigned short* __restrict__ wkh,
                                                   const unsigned short* __restrict__ wkl,
                                                   float* __restrict__ Qo,
                                                   float* __restrict__ Ko) {
  __shared__ unsigned short Ah[2][128 * 32];   // 2 x 8 KB
  __shared__ unsigned short Av[2][128 * 32];
  __shared__ unsigned short Bh[2][128 * 32];   // rows 0-63 = Wq, 64-127 = Wk
  __shared__ unsigned short Bv[2][128 * 32];   // 64 KB total
  const int tid = threadIdx.x;
  const int bm = blockIdx.x * 128;
  const int bn = blockIdx.y * 64;      // col offset within each weight
  const int wv = tid >> 6, lane = tid & 63;
  const int wm = wv & 1, wn = wv >> 1;  // wn: 0=Q, 1=K
  const int lrow = lane & 15, lquad = lane >> 4;

  const int sr = tid >> 2, qg = tid & 3;
  const int qs = qg ^ ((sr >> 1) & 3);   // same swz for row sr and 64+sr

  f32x4 acc0[4][4], acc1[4][4];
  #pragma unroll
  for (int i = 0; i < 4; ++i)
    #pragma unroll
    for (int j = 0; j < 4; ++j) {
      acc0[i][j] = (f32x4){0.f, 0.f, 0.f, 0.f};
      acc1[i][j] = (f32x4){0.f, 0.f, 0.f, 0.f};
    }

  // prologue: stage iter 0 into buffer 0
  {
    uint4 a0H = *(const uint4*)(xhp + (size_t)(bm + sr) * C + qg * 8);
    uint4 a0L = *(const uint4*)(xlp + (size_t)(bm + sr) * C + qg * 8);
    uint4 a1H = *(const uint4*)(xhp + (size_t)(bm + 64 + sr) * C + qg * 8);
    uint4 a1L = *(const uint4*)(xlp + (size_t)(bm + 64 + sr) * C + qg * 8);
    uint4 bqH = *(const uint4*)(wqh + (size_t)(bn + sr) * C + qg * 8);
    uint4 bqL = *(const uint4*)(wql + (size_t)(bn + sr) * C + qg * 8);
    uint4 bkH = *(const uint4*)(wkh + (size_t)(bn + sr) * C + qg * 8);
    uint4 bkL = *(const uint4*)(wkl + (size_t)(bn + sr) * C + qg * 8);
    *(uint4*)&Ah[0][sr * 32 + qs * 8] = a0H;
    *(uint4*)&Av[0][sr * 32 + qs * 8] = a0L;
    *(uint4*)&Ah[0][(64 + sr) * 32 + qs * 8] = a1H;
    *(uint4*)&Av[0][(64 + sr) * 32 + qs * 8] = a1L;
    *(uint4*)&Bh[0][sr * 32 + qs * 8] = bqH;
    *(uint4*)&Bv[0][sr * 32 + qs * 8] = bqL;
    *(uint4*)&Bh[0][(64 + sr) * 32 + qs * 8] = bkH;
    *(uint4*)&Bv[0][(64 + sr) * 32 + qs * 8] = bkL;
  }
  __syncthreads();

  const int niter = C / 32;
  for (int it = 0; it < niter; ++it) {
    const int cur = it & 1;
    const bool has = (it + 1) < niter;
    uint4 a0H, a0L, a1H, a1L, bqH, bqL, bkH, bkL;
    if (has) {
      const int k0 = (it + 1) * 32;
      a0H = *(const uint4*)(xhp + (size_t)(bm + sr) * C + k0 + qg * 8);
      a0L = *(const uint4*)(xlp + (size_t)(bm + sr) * C + k0 + qg * 8);
      a1H = *(const uint4*)(xhp + (size_t)(bm + 64 + sr) * C + k0 + qg * 8);
      a1L = *(const uint4*)(xlp + (size_t)(bm + 64 + sr) * C + k0 + qg * 8);
      bqH = *(const uint4*)(wqh + (size_t)(bn + sr) * C + k0 + qg * 8);
      bqL = *(const uint4*)(wql + (size_t)(bn + sr) * C + k0 + qg * 8);
      bkH = *(const uint4*)(wkh + (size_t)(bn + sr) * C + k0 + qg * 8);
      bkL = *(const uint4*)(wkl + (size_t)(bn + sr) * C + k0 + qg * 8);
    }
    f16x8 ah[4], av[4], bh[4], bv[4];
    #pragma unroll
    for (int mi = 0; mi < 4; ++mi) {
      const int r = wm * 64 + mi * 16 + lrow;
      const int q = lquad ^ ((r >> 1) & 3);
      ah[mi] = *(const f16x8*)&Ah[cur][r * 32 + q * 8];
      av[mi] = *(const f16x8*)&Av[cur][r * 32 + q * 8];
    }
    #pragma unroll
    for (int ni = 0; ni < 4; ++ni) {
      const int r = wn * 64 + ni * 16 + lrow;
      const int q = lquad ^ ((r >> 1) & 3);
      bh[ni] = *(const f16x8*)&Bh[cur][r * 32 + q * 8];
      bv[ni] = *(const f16x8*)&Bv[cur][r * 32 + q * 8];
    }
    #pragma unroll
    for (int mi = 0; mi < 4; ++mi)
      #pragma unroll
      for (int ni = 0; ni < 4; ++ni) {
        acc0[mi][ni] = __builtin_amdgcn_mfma_f32_16x16x32_f16(ah[mi], bh[ni], acc0[mi][ni], 0, 0, 0);
        acc1[mi][ni] = __builtin_amdgcn_mfma_f32_16x16x32_f16(ah[mi], bv[ni], acc1[mi][ni], 0, 0, 0);
        acc1[mi][ni] = __builtin_amdgcn_mfma_f32_16x16x32_f16(av[mi], bh[ni], acc1[mi][ni], 0, 0, 0);
      }
    if (has) {
      const int nxt = cur ^ 1;
      *(uint4*)&Ah[nxt][sr * 32 + qs * 8] = a0H;
      *(uint4*)&Av[nxt][sr * 32 + qs * 8] = a0L;
      *(uint4*)&Ah[nxt][(64 + sr) * 32 + qs * 8] = a1H;
      *(uint4*)&Av[nxt][(64 + sr) * 32 + qs * 8] = a1L;
      *(uint4*)&Bh[nxt][sr * 32 + qs * 8] = bqH;
      *(uint4*)&Bv[nxt][sr * 32 + qs * 8] = bqL;
      *(uint4*)&Bh[nxt][(64 + sr) * 32 + qs * 8] = bkH;
      *(uint4*)&Bv[nxt][(64 + sr) * 32 + qs * 8] = bkL;
    }
    __syncthreads();
  }
  // epilogue: C/D layout col=lane&15, row=lquad*4+r (m89-verified)
  float* __restrict__ Cc = wn ? Ko : Qo;
  #pragma unroll
  for (int mi = 0; mi < 4; ++mi)
    #pragma unroll
    for (int ni = 0; ni < 4; ++ni)
      #pragma unroll
      for (int r = 0; r < 4; ++r) {
        int row = bm + wm * 64 + mi * 16 + lquad * 4 + r;
        int col = bn + ni * 16 + lrow;
        Cc[(size_t)row * C + col] = acc0[mi][ni][r] * S0F + acc1[mi][ni][r] * S1F;
      }
}

// ---------------- 1-term fp16-hi GEMM (V and proj; smooth paths) ----------
__global__ __launch_bounds__(256) void gemm_h1(const unsigned short* __restrict__ A,
                                               const unsigned short* __restrict__ B,
                                               float* __restrict__ Cc) {
  __shared__ unsigned short Ah[2][SBM * SBK];   // 2 x 4 KB
  __shared__ unsigned short Bh[2][SBN * SBK];   // 2 x 8 KB  (24 KB)
  const int tid = threadIdx.x;
  const int bm = blockIdx.x * SBM;
  const int bn = blockIdx.y * SBN;
  const int wv = tid >> 6, lane = tid & 63;
  const int wm = wv & 1, wn = wv >> 1;
  const int lrow = lane & 15, lquad = lane >> 4;

  const int a_row = tid >> 2, qg = tid & 3;
  const int a_qs = qg ^ ((a_row >> 1) & 3);
  const int b_row0 = tid >> 2;
  const int b_qs = qg ^ ((b_row0 >> 1) & 3);

  f32x4 acc[2][4];
  #pragma unroll
  for (int i = 0; i < 2; ++i)
    #pragma unroll
    for (int j = 0; j < 4; ++j) acc[i][j] = (f32x4){0.f, 0.f, 0.f, 0.f};

  {
    uint4 av = *(const uint4*)(A + (size_t)(bm + a_row) * C + qg * 8);
    uint4 b0 = *(const uint4*)(B + (size_t)(bn + b_row0) * C + qg * 8);
    uint4 b1 = *(const uint4*)(B + (size_t)(bn + 64 + b_row0) * C + qg * 8);
    *(uint4*)&Ah[0][a_row * SBK + a_qs * 8] = av;
    *(uint4*)&Bh[0][b_row0 * SBK + b_qs * 8] = b0;
    *(uint4*)&Bh[0][(64 + b_row0) * SBK + b_qs * 8] = b1;
  }
  __syncthreads();

  const int niter = C / SBK;
  for (int it = 0; it < niter; ++it) {
    const int cur = it & 1;
    const bool has = (it + 1) < niter;
    uint4 avn, b0n, b1n;
    if (has) {
      const int k0 = (it + 1) * SBK;
      avn = *(const uint4*)(A + (size_t)(bm + a_row) * C + k0 + qg * 8);
      b0n = *(const uint4*)(B + (size_t)(bn + b_row0) * C + k0 + qg * 8);
      b1n = *(const uint4*)(B + (size_t)(bn + 64 + b_row0) * C + k0 + qg * 8);
    }
    f16x8 af[2], bfr[4];
    #pragma unroll
    for (int mi = 0; mi < 2; ++mi) {
      const int r = wm * 32 + mi * 16 + lrow;
      const int q = lquad ^ ((r >> 1) & 3);
      af[mi] = *(const f16x8*)&Ah[cur][r * SBK + q * 8];
    }
    #pragma unroll
    for (int ni = 0; ni < 4; ++ni) {
      const int r = wn * 64 + ni * 16 + lrow;
      const int q = lquad ^ ((r >> 1) & 3);
      bfr[ni] = *(const f16x8*)&Bh[cur][r * SBK + q * 8];
    }
    #pragma unroll
    for (int mi = 0; mi < 2; ++mi)
      #pragma unroll
      for (int ni = 0; ni < 4; ++ni)
        acc[mi][ni] = __builtin_amdgcn_mfma_f32_16x16x32_f16(af[mi], bfr[ni], acc[mi][ni], 0, 0, 0);
    if (has) {
      const int nxt = cur ^ 1;
      *(uint4*)&Ah[nxt][a_row * SBK + a_qs * 8] = avn;
      *(uint4*)&Bh[nxt][b_row0 * SBK + b_qs * 8] = b0n;
      *(uint4*)&Bh[nxt][(64 + b_row0) * SBK + b_qs * 8] = b1n;
    }
    __syncthreads();
  }
  #pragma unroll
  for (int mi = 0; mi < 2; ++mi)
    #pragma unroll
    for (int ni = 0; ni < 4; ++ni)
      #pragma unroll
      for (int r = 0; r < 4; ++r) {
        int row = bm + wm * 32 + mi * 16 + lquad * 4 + r;
        int col = bn + wn * 64 + ni * 16 + lrow;
        Cc[(size_t)row * C + col] = acc[mi][ni][r] * S0F;
      }
}

// ---------------- Q/K GEMM with IN-KERNEL split (round-5 fallback) --------
__device__ __forceinline__ void split8(const float4 v0, const float4 v1,
                                       uint4& hi, uint4& lo) {
  float s[8] = {v0.x * PRESC, v0.y * PRESC, v0.z * PRESC, v0.w * PRESC,
                v1.x * PRESC, v1.y * PRESC, v1.z * PRESC, v1.w * PRESC};
  union { uint4 u; f16 h[8]; } H, L;
  #pragma unroll
  for (int i = 0; i < 8; ++i) {
    f16 h2 = (f16)s[i];
    float d = s[i] - (float)h2;
    H.h[i] = h2;
    L.h[i] = (f16)(d * 2048.0f);
  }
  hi = H.u; lo = L.u;
}

__global__ __launch_bounds__(256, 2) void gemm_qk_split16(const float* __restrict__ A,
                                                          const float* __restrict__ Wq,
                                                          const float* __restrict__ Wk,
                                                          float* __restrict__ Qo,
                                                          float* __restrict__ Ko) {
  const float* __restrict__ Bw = blockIdx.z ? Wk : Wq;
  float* __restrict__ Cc = blockIdx.z ? Ko : Qo;
  __shared__ unsigned short Ah[2][SBM * SBK];
  __shared__ unsigned short Av[2][SBM * SBK];
  __shared__ unsigned short Bh[2][SBN * SBK];
  __shared__ unsigned short Bv[2][SBN * SBK];
  const int tid = threadIdx.x;
  const int bm = blockIdx.x * SBM;
  const int bn = blockIdx.y * SBN;
  const int wv = tid >> 6, lane = tid & 63;
  const int wm = wv & 1, wn = wv >> 1;
  const int lrow = lane & 15, lquad = lane >> 4;

  const int a_row = tid >> 2, qg = tid & 3;
  const int a_qs = qg ^ ((a_row >> 1) & 3);
  const int b_row0 = tid >> 2;
  const int b_qs = qg ^ ((b_row0 >> 1) & 3);

  f32x4 acc[3][2][4];
  #pragma unroll
  for (int g = 0; g < 3; ++g)
    #pragma unroll
    for (int i = 0; i < 2; ++i)
      #pragma unroll
      for (int j = 0; j < 4; ++j) acc[g][i][j] = (f32x4){0.f, 0.f, 0.f, 0.f};

  {
    const float* pA  = A  + (size_t)(bm + a_row) * C + qg * 8;
    const float* pB0 = Bw + (size_t)(bn + b_row0) * C + qg * 8;
    const float* pB1 = Bw + (size_t)(bn + 64 + b_row0) * C + qg * 8;
    uint4 h, l;
    split8(*(const float4*)pA, *(const float4*)(pA + 4), h, l);
    *(uint4*)&Ah[0][a_row * SBK + a_qs * 8] = h;
    *(uint4*)&Av[0][a_row * SBK + a_qs * 8] = l;
    split8(*(const float4*)pB0, *(const float4*)(pB0 + 4), h, l);
    *(uint4*)&Bh[0][b_row0 * SBK + b_qs * 8] = h;
    *(uint4*)&Bv[0][b_row0 * SBK + b_qs * 8] = l;
    split8(*(const float4*)pB1, *(const float4*)(pB1 + 4), h, l);
    *(uint4*)&Bh[0][(64 + b_row0) * SBK + b_qs * 8] = h;
    *(uint4*)&Bv[0][(64 + b_row0) * SBK + b_qs * 8] = l;
  }
  __syncthreads();

  const int niter = C / SBK;
  for (int it = 0; it < niter; ++it) {
    const int cur = it & 1;
    const bool has = (it + 1) < niter;
    float4 a0n, a1n, b00n, b01n, b10n, b11n;
    if (has) {
      const int k0 = (it + 1) * SBK;
      const float* pA  = A  + (size_t)(bm + a_row) * C + k0 + qg * 8;
      const float* pB0 = Bw + (size_t)(bn + b_row0) * C + k0 + qg * 8;
      const float* pB1 = Bw + (size_t)(bn + 64 + b_row0) * C + k0 + qg * 8;
      a0n = *(const float4*)pA;   a1n = *(const float4*)(pA + 4);
      b00n = *(const float4*)pB0; b01n = *(const float4*)(pB0 + 4);
      b10n = *(const float4*)pB1; b11n = *(const float4*)(pB1 + 4);
    }
    f16x8 ah[2], av[2], bh[4], bv[4];
    #pragma unroll
    for (int mi = 0; mi < 2; ++mi) {
      const int r = wm * 32 + mi * 16 + lrow;
      const int q = lquad ^ ((r >> 1) & 3);
      ah[mi] = *(const f16x8*)&Ah[cur][r * SBK + q * 8];
      av[mi] = *(const f16x8*)&Av[cur][r * SBK + q * 8];
    }
    #pragma unroll
    for (int ni = 0; ni < 4; ++ni) {
      const int r = wn * 64 + ni * 16 + lrow;
      const int q = lquad ^ ((r >> 1) & 3);
      bh[ni] = *(const f16x8*)&Bh[cur][r * SBK + q * 8];
      bv[ni] = *(const f16x8*)&Bv[cur][r * SBK + q * 8];
    }
    #pragma unroll
    for (int mi = 0; mi < 2; ++mi)
      #pragma unroll
      for (int ni = 0; ni < 4; ++ni) {
        acc[0][mi][ni] = __builtin_amdgcn_mfma_f32_16x16x32_f16(ah[mi], bh[ni], acc[0][mi][ni], 0, 0, 0);
        acc[1][mi][ni] = __builtin_amdgcn_mfma_f32_16x16x32_f16(ah[mi], bv[ni], acc[1][mi][ni], 0, 0, 0);
        acc[1][mi][ni] = __builtin_amdgcn_mfma_f32_16x16x32_f16(av[mi], bh[ni], acc[1][mi][ni], 0, 0, 0);
        acc[2][mi][ni] = __builtin_amdgcn_mfma_f32_16x16x32_f16(av[mi], bv[ni], acc[2][mi][ni], 0, 0, 0);
      }
    if (has) {
      const int nxt = cur ^ 1;
      uint4 h, l;
      split8(a0n, a1n, h, l);
      *(uint4*)&Ah[nxt][a_row * SBK + a_qs * 8] = h;
      *(uint4*)&Av[nxt][a_row * SBK + a_qs * 8] = l;
      split8(b00n, b01n, h, l);
      *(uint4*)&Bh[nxt][b_row0 * SBK + b_qs * 8] = h;
      *(uint4*)&Bv[nxt][b_row0 * SBK + b_qs * 8] = l;
      split8(b10n, b11n, h, l);
      *(uint4*)&Bh[nxt][(64 + b_row0) * SBK + b_qs * 8] = h;
      *(uint4*)&Bv[nxt][(64 + b_row0) * SBK + b_qs * 8] = l;
    }
    __syncthreads();
  }
  #pragma unroll
  for (int mi = 0; mi < 2; ++mi)
    #pragma unroll
    for (int ni = 0; ni < 4; ++ni)
      #pragma unroll
      for (int r = 0; r < 4; ++r) {
        int row = bm + wm * 32 + mi * 16 + lquad * 4 + r;
        int col = bn + wn * 64 + ni * 16 + lrow;
        float v = acc[0][mi][ni][r] * S0F + (acc[1][mi][ni][r] * S1F + acc[2][mi][ni][r] * S2F);
        Cc[(size_t)row * C + col] = v;
      }
}

// ---------------- bf16 MFMA GEMM (fallback path only) ---------------------
#define VBM 64
#define VBN 128
#define VBK 32

__global__ __launch_bounds__(256) void gemm_bf16n(const unsigned short* __restrict__ A,
                                                  const unsigned short* __restrict__ B,
                                                  float* __restrict__ Cc) {
  __shared__ unsigned short Al[2][VBM * VBK];
  __shared__ unsigned short Bl[2][VBN * VBK];
  const int tid = threadIdx.x;
  const int bm = blockIdx.x * VBM;
  const int bn = blockIdx.y * VBN;
  const int wv = tid >> 6, lane = tid & 63;
  const int wm = wv & 1, wn = wv >> 1;
  const int lrow = lane & 15, lquad = lane >> 4;

  const int a_row = tid >> 2, qg = tid & 3;
  const int a_qs = qg ^ ((a_row >> 1) & 3);
  const int b_row0 = tid >> 2;
  const int b_qs = qg ^ ((b_row0 >> 1) & 3);

  f32x4 acc[2][4];
  #pragma unroll
  for (int i = 0; i < 2; ++i)
    #pragma unroll
    for (int j = 0; j < 4; ++j) acc[i][j] = (f32x4){0.f, 0.f, 0.f, 0.f};

  {
    uint4 av = *(const uint4*)(A + (size_t)(bm + a_row) * C + qg * 8);
    uint4 b0 = *(const uint4*)(B + (size_t)(bn + b_row0) * C + qg * 8);
    uint4 b1 = *(const uint4*)(B + (size_t)(bn + 64 + b_row0) * C + qg * 8);
    *(uint4*)&Al[0][a_row * VBK + a_qs * 8] = av;
    *(uint4*)&Bl[0][b_row0 * VBK + b_qs * 8] = b0;
    *(uint4*)&Bl[0][(64 + b_row0) * VBK + b_qs * 8] = b1;
  }
  __syncthreads();

  const int niter = C / VBK;
  for (int it = 0; it < niter; ++it) {
    const int cur = it & 1;
    const bool has = (it + 1) < niter;
    uint4 avn, b0n, b1n;
    if (has) {
      const int k0 = (it + 1) * VBK;
      avn = *(const uint4*)(A + (size_t)(bm + a_row) * C + k0 + qg * 8);
      b0n = *(const uint4*)(B + (size_t)(bn + b_row0) * C + k0 + qg * 8);
      b1n = *(const uint4*)(B + (size_t)(bn + 64 + b_row0) * C + k0 + qg * 8);
    }
    s16x8 af[2], bfr[4];
    #pragma unroll
    for (int mi = 0; mi < 2; ++mi) {
      const int r = wm * 32 + mi * 16 + lrow;
      const int q = lquad ^ ((r >> 1) & 3);
      af[mi] = *(const s16x8*)&Al[cur][r * VBK + q * 8];
    }
    #pragma unroll
    for (int ni = 0; ni < 4; ++ni) {
      const int r = wn * 64 + ni * 16 + lrow;
      const int q = lquad ^ ((r >> 1) & 3);
      bfr[ni] = *(const s16x8*)&Bl[cur][r * VBK + q * 8];
    }
    #pragma unroll
    for (int mi = 0; mi < 2; ++mi)
      #pragma unroll
      for (int ni = 0; ni < 4; ++ni)
        acc[mi][ni] = __builtin_amdgcn_mfma_f32_16x16x32_bf16(af[mi], bfr[ni], acc[mi][ni], 0, 0, 0);
    if (has) {
      const int nxt = cur ^ 1;
      *(uint4*)&Al[nxt][a_row * VBK + a_qs * 8] = avn;
      *(uint4*)&Bl[nxt][b_row0 * VBK + b_qs * 8] = b0n;
      *(uint4*)&Bl[nxt][(64 + b_row0) * VBK + b_qs * 8] = b1n;
    }
    __syncthreads();
  }
  #pragma unroll
  for (int mi = 0; mi < 2; ++mi)
    #pragma unroll
    for (int ni = 0; ni < 4; ++ni)
      #pragma unroll
      for (int r = 0; r < 4; ++r) {
        int row = bm + wm * 32 + mi * 16 + lquad * 4 + r;
        int col = bn + wn * 64 + ni * 16 + lrow;
        Cc[(size_t)row * C + col] = acc[mi][ni][r];
      }
}

// ---------------- zero worklist counter ----------------
__global__ void zero_ctr(int* __restrict__ ctr) {
  if (threadIdx.x == 0) ctr[0] = 0;
}

// ---------------- RoPE + RMSNorm + bucket codes + marginal-row flagging ----
__global__ __launch_bounds__(256) void rope_fused(float* __restrict__ Qb,
                                                  float* __restrict__ Kb,
                                                  const float* __restrict__ cosb,
                                                  const float* __restrict__ sinb,
                                                  const float* __restrict__ Wdq,
                                                  const float* __restrict__ Wdk,
                                                  int* __restrict__ qcodes,
                                                  int* __restrict__ kcodes,
                                                  int* __restrict__ wl,
                                                  int* __restrict__ ctr) {
  float* __restrict__ buf = blockIdx.y ? Kb : Qb;
  const float* __restrict__ Wd = blockIdx.y ? Wdk : Wdq;
  int* __restrict__ codes = blockIdx.y ? kcodes : qcodes;
  int wave = (blockIdx.x << 2) + (threadIdx.x >> 6);
  int lane = threadIdx.x & 63;
  int t = wave / NH, h = wave % NH;
  size_t base = (size_t)t * C + h * HD;
  float x1 = buf[base + lane];
  float x2 = buf[base + lane + 64];
  float c = cosb[t * 64 + lane];
  float s = sinb[t * 64 + lane];
  float r1 = x1 * c + x2 * s;
  float r2 = x2 * c - x1 * s;       // -x1*s + x2*c
  float ss = wave_sum(r1 * r1 + r2 * r2);
  float inv = 1.0f / sqrtf(ss * (1.0f / 128.0f) + 1e-6f);
  r1 *= inv; r2 *= inv;
  buf[base + lane] = r1;
  buf[base + lane + 64] = r2;
  int code = 0;
  bool marg = false;
  #pragma unroll
  for (int kk = 0; kk < 7; ++kk) {
    float z = r1 * Wd[kk * HD + lane] + r2 * Wd[kk * HD + lane + 64];
    z = wave_sum(z);
    float sig = 1.0f / (1.0f + expf(-z));
    float d = sig * 1.99f - 1.0f;
    if (d >= 0.f) code |= (1 << kk);
    marg |= (fabsf(d) < MARG);
  }
  if (lane == 0) {
    codes[h * T + t] = code;
    if (marg) {
      int i = atomicAdd(ctr, 1);
      if ((unsigned)i < (unsigned)WL_CAP) wl[i] = ((int)blockIdx.y << 15) | (h << 11) | t;
    }
  }
}

// ---------------- exact code recompute for marginal rows (FROZEN path) -----
__global__ __launch_bounds__(64) void fix_codes(const float* __restrict__ x,
                                                const float* __restrict__ Wq,
                                                const float* __restrict__ Wk,
                                                const float* __restrict__ cosb,
                                                const float* __restrict__ sinb,
                                                const float* __restrict__ Wdq,
                                                const float* __restrict__ Wdk,
                                                int* __restrict__ qc,
                                                int* __restrict__ kc,
                                                const int* __restrict__ wl,
                                                const int* __restrict__ ctr) {
  const int n = min(max(ctr[0], 0), WL_CAP);
  const int lane = threadIdx.x;
  for (int e = blockIdx.x; e < n; e += gridDim.x) {
    const int ent = wl[e];
    const int isK = (ent >> 15) & 1;
    const int h = (ent >> 11) & 15;
    const int t = ent & 2047;
    const float* __restrict__ W  = isK ? Wk : Wq;
    const float* __restrict__ Wd = isK ? Wdk : Wdq;
    int* __restrict__ codes = isK ? kc : qc;

    const float* xr = x + (size_t)t * C;
    const float* w0 = W + (size_t)(h * HD + lane) * C;
    const float* w1 = W + (size_t)(h * HD + lane + 64) * C;
    float p0[4] = {0.f, 0.f, 0.f, 0.f};
    float p1[4] = {0.f, 0.f, 0.f, 0.f};
    for (int k = 0; k < C; k += 4) {
      float4 xv = *(const float4*)(xr + k);
      float4 a = *(const float4*)(w0 + k);
      float4 b = *(const float4*)(w1 + k);
      p0[0] += xv.x * a.x; p0[1] += xv.y * a.y;
      p0[2] += xv.z * a.z; p0[3] += xv.w * a.w;
      p1[0] += xv.x * b.x; p1[1] += xv.y * b.y;
      p1[2] += xv.z * b.z; p1[3] += xv.w * b.w;
    }
    float x1 = (p0[0] + p0[1]) + (p0[2] + p0[3]);   // frozen merge
    float x2 = (p1[0] + p1[1]) + (p1[2] + p1[3]);
    float c = cosb[t * 64 + lane];
    float s = sinb[t * 64 + lane];
    float r1 = x1 * c + x2 * s;
    float r2 = x2 * c - x1 * s;
    float ss = wave_sum(r1 * r1 + r2 * r2);
    float inv = 1.0f / sqrtf(ss * (1.0f / 128.0f) + 1e-6f);
    r1 *= inv; r2 *= inv;
    int code = 0;
    #pragma unroll
    for (int kk = 0; kk < 7; ++kk) {
      float z = r1 * Wd[kk * HD + lane] + r2 * Wd[kk * HD + lane + 64];
      z = wave_sum(z);
      float sig = 1.0f / (1.0f + expf(-z));
      if (sig * 1.99f >= 1.0f) code |= (1 << kk);
    }
    if (lane == 0) codes[h * T + t] = code;
  }
}

// ---------------- sparse ballot-scan attention (validated) ---------------
__global__ __launch_bounds__(256) void attn_sparse(const float* __restrict__ Q,
                                                   const float* __restrict__ Kn,
                                                   const float* __restrict__ V,
                                                   const int* __restrict__ qc,
                                                   const int* __restrict__ kc,
                                                   float* __restrict__ Y) {
  const int tid = threadIdx.x;
  const int lane = tid & 63;
  const int wave_id = blockIdx.x * 4 + (tid >> 6);   // [0, T*NH)
  const int h = wave_id & (NH - 1);
  const int qrow = wave_id >> 4;
  const size_t hb = (size_t)h * HD;

  const float q0 = Q[(size_t)qrow * C + hb + lane];
  const float q1 = Q[(size_t)qrow * C + hb + lane + 64];
  const int qcode = qc[h * T + qrow];
  const int* kch = kc + h * T;

  float m = -1e30f, l = 0.f, acc0 = 0.f, acc1 = 0.f;

  const int nchunks = (qrow >> 6) + 1;
  int kcj = kch[lane];
  for (int ci = 0; ci < nchunks; ++ci) {
    const int j0 = ci << 6;
    const int cur = kcj;
    if (ci + 1 < nchunks) kcj = kch[j0 + 64 + lane];
    unsigned long long mask = __ballot((cur == qcode) && (j0 + lane <= qrow));
    while (mask) {
      const int j = j0 + (__ffsll((long long)mask) - 1);
      mask &= mask - 1;
      const float* kr = Kn + (size_t)j * C + hb;
      const float* vr = V + (size_t)j * C + hb;
      const float k0v = kr[lane], k1v = kr[lane + 64];
      const float v0 = vr[lane], v1 = vr[lane + 64];
      const float s = wave_sum(q0 * k0v + q1 * k1v) * SCALE;
      const float m_new = fmaxf(m, s);
      const float alpha = __expf(m - m_new);
      const float p = __expf(s - m_new);
      l = l * alpha + p;
      acc0 = acc0 * alpha + p * v0;
      acc1 = acc1 * alpha + p * v1;
      m = m_new;
    }
  }
  const float invl = (l > 0.f) ? 1.0f / l : 0.f;
  Y[(size_t)qrow * C + hb + lane] = acc0 * invl;
  Y[(size_t)qrow * C + hb + lane + 64] = acc1 * invl;
}

extern "C" void kernel_launch(void* const* d_in, const int* in_sizes, int n_in,
                              void* d_out, int out_size, void* d_ws, size_t ws_size,
                              hipStream_t stream) {
  (void)in_sizes; (void)n_in; (void)out_size;
  const float* x     = (const float*)d_in[0];
  const float* cosb  = (const float*)d_in[1];
  const float* sinb  = (const float*)d_in[2];
  const float* Wq    = (const float*)d_in[3];
  const float* Wk    = (const float*)d_in[4];
  const float* Wv    = (const float*)d_in[5];
  const float* Wproj = (const float*)d_in[6];
  const float* Wdq   = (const float*)d_in[7];
  const float* Wdk   = (const float*)d_in[8];
  float* out = (float*)d_out;

  const size_t MB = 1024 * 1024;
  char* ws = (char*)d_ws;
  const int n4 = T * C / 4;

  if (ws_size >= (size_t)64 * MB) {
    // ---- fast path, 64 MiB packed layout (liveness identical to round 7) --
    unsigned short* xh  = (unsigned short*)(ws);
    unsigned short* xl  = (unsigned short*)(ws + 8 * MB);
    unsigned short* wqh = (unsigned short*)(ws + 16 * MB);
    unsigned short* wql = (unsigned short*)(ws + 24 * MB);
    unsigned short* wkh = (unsigned short*)(ws + 32 * MB);
    unsigned short* wkl = (unsigned short*)(ws + 40 * MB);
    float* K = (float*)(ws + 48 * MB);
    unsigned short* wvh = (unsigned short*)(ws + 16 * MB);   // after QK gemm
    float* V = (float*)(ws + 24 * MB);                        // after QK gemm
    int* qc  = (int*)(ws + 40 * MB);                          // after QK gemm
    int* kc  = qc + NH * T;
    int* ctr = kc + NH * T;
    int* wl  = ctr + 16;
    float* Y = (float*)(ws);                                  // after V gemm
    unsigned short* yh  = (unsigned short*)(ws + 16 * MB);    // after attn
    unsigned short* wph = (unsigned short*)(ws + 24 * MB);    // after attn
    float* Q = out;                 // Q dead before proj overwrites d_out

    pre_split3<<<dim3(1024, 3), 256, 0, stream>>>(x, Wq, Wk, xh, xl, wqh, wql, wkh, wkl, n4);
    zero_ctr<<<1, 64, 0, stream>>>(ctr);   // AFTER wkl is fully written (stream order)
    gemm_qkf<<<dim3(T / 128, C / 64), 256, 0, stream>>>(xh, xl, wqh, wql, wkh, wkl, Q, K);
    to_f16h<<<2048, 256, 0, stream>>>(Wv, wvh, n4);           // wqh dead
    gemm_h1<<<dim3(T / SBM, C / SBN), 256, 0, stream>>>(xh, wvh, V);  // wql/wkh dead
    rope_fused<<<dim3(T * NH / 4, 2), 256, 0, stream>>>(Q, K, cosb, sinb, Wdq, Wdk, qc, kc, wl, ctr);
    fix_codes<<<256, 64, 0, stream>>>(x, Wq, Wk, cosb, sinb, Wdq, Wdk, qc, kc, wl, ctr);
    attn_sparse<<<T * NH / 4, 256, 0, stream>>>(Q, K, V, qc, kc, Y);  // xh/xl dead
    post_h2<<<dim3(1024, 2), 256, 0, stream>>>(Y, Wproj, yh, wph, n4); // wvh, V dead
    gemm_h1<<<dim3(T / SBM, C / SBN), 256, 0, stream>>>(yh, wph, out);
  } else {
    // ---- fallback: round-5 proven path (56.26 MiB layout) ----
    float* Kbuf = (float*)ws;
    float* V    = (float*)(ws + 16 * MB);
    float* Y    = (float*)(ws + 32 * MB);
    unsigned short* Wbf = (unsigned short*)(ws + 48 * MB);
    unsigned short* xbf = (unsigned short*)Y;
    unsigned short* Ybf = (unsigned short*)Kbuf;
    float* Q    = out;
    int* qc  = (int*)(Wbf + (size_t)T * C);
    int* kc  = qc + NH * T;
    int* ctr = kc + NH * T;
    int* wl  = ctr + 16;

    to_bf16<<<2048, 256, 0, stream>>>(x, xbf, n4);
    to_bf16<<<2048, 256, 0, stream>>>(Wv, Wbf, n4);
    gemm_bf16n<<<dim3(T / VBM, C / VBN), 256, 0, stream>>>(xbf, Wbf, V);
    gemm_qk_split16<<<dim3(T / SBM, C / SBN, 2), 256, 0, stream>>>(x, Wq, Wk, Q, Kbuf);
    zero_ctr<<<1, 64, 0, stream>>>(ctr);
    rope_fused<<<dim3(T * NH / 4, 2), 256, 0, stream>>>(Q, Kbuf, cosb, sinb, Wdq, Wdk, qc, kc, wl, ctr);
    fix_codes<<<256, 64, 0, stream>>>(x, Wq, Wk, cosb, sinb, Wdq, Wdk, qc, kc, wl, ctr);
    attn_sparse<<<T * NH / 4, 256, 0, stream>>>(Q, Kbuf, V, qc, kc, Y);
    to_bf16<<<2048, 256, 0, stream>>>(Y, Ybf, n4);
    to_bf16<<<2048, 256, 0, stream>>>(Wproj, Wbf, n4);
    gemm_bf16n<<<dim3(T / VBM, C / VBN), 256, 0, stream>>>(Ybf, Wbf, out);
  }
}